// Round 1
// baseline (518.541 us; speedup 1.0000x reference)
//
#include <hip/hip_runtime.h>
#include <hip/hip_bf16.h>
#include <math.h>

#define S_LEN 4096
#define DMODEL 768
#define NHEAD 12
#define HDIM 64
#define DFF_ 3072
#define MROWS 8192  // B*S

typedef __bf16 bf16;
typedef __bf16 bf16x4 __attribute__((ext_vector_type(4)));
typedef __bf16 bf16x8 __attribute__((ext_vector_type(8)));
typedef float f32x4 __attribute__((ext_vector_type(4)));
typedef short s16x4 __attribute__((ext_vector_type(4)));

union F4 { float4 v; float f[4]; };
union U2 { bf16 h[2]; unsigned u; };
union U8 { unsigned u[4]; bf16x8 v; };

// 16x16x16 bf16 MFMA: B-operand layout B[k=quad*4+j][n=l] == S^T C-layout,
// so softmax'd P feeds PV directly with ZERO cross-lane movement.
#if __has_builtin(__builtin_amdgcn_mfma_f32_16x16x16bf16_1k)
typedef s16x4 mf16_t;
#define MFMA16(a, b, c) __builtin_amdgcn_mfma_f32_16x16x16bf16_1k((a), (b), (c), 0, 0, 0)
#define HAVE_MFMA16 1
#elif __has_builtin(__builtin_amdgcn_mfma_f32_16x16x16_bf16)
typedef bf16x4 mf16_t;
#define MFMA16(a, b, c) __builtin_amdgcn_mfma_f32_16x16x16_bf16((a), (b), (c), 0, 0, 0)
#define HAVE_MFMA16 1
#else
#define HAVE_MFMA16 0
#endif

#if HAVE_MFMA16
union U4 { unsigned u[2]; mf16_t v; };
#endif

__device__ __forceinline__ void gld_lds16(void* lds, const void* g) {
    __builtin_amdgcn_global_load_lds(
        (const __attribute__((address_space(1))) unsigned int*)g,
        (__attribute__((address_space(3))) unsigned int*)lds, 16, 0, 0);
}

// ---------------- LayerNorm (optionally zero-fills the 768-float zbias buf) ----------------
template<typename OUT>
__global__ __launch_bounds__(256) void ln_kernel(const float* __restrict__ x,
                                                 const float* __restrict__ g,
                                                 const float* __restrict__ bta,
                                                 OUT* __restrict__ out,
                                                 float* __restrict__ zb) {
    const int row = blockIdx.x;
    const int t = threadIdx.x;
    // zbias zero-fill: runs at LN2 time (after vb is dead, before FF2 reads it)
    if (zb && row == 0 && t < 192)
        ((float4*)zb)[t] = make_float4(0.f, 0.f, 0.f, 0.f);
    const float* xr = x + (size_t)row * DMODEL;
    float v0 = xr[t], v1 = xr[t + 256], v2 = xr[t + 512];
    float s = v0 + v1 + v2;
    float ss = v0 * v0 + v1 * v1 + v2 * v2;
    for (int o = 32; o > 0; o >>= 1) {
        s += __shfl_down(s, o, 64);
        ss += __shfl_down(ss, o, 64);
    }
    __shared__ float sm[4], sm2[4];
    const int w = t >> 6, lane = t & 63;
    if (lane == 0) { sm[w] = s; sm2[w] = ss; }
    __syncthreads();
    s = sm[0] + sm[1] + sm[2] + sm[3];
    ss = sm2[0] + sm2[1] + sm2[2] + sm2[3];
    const float mu = s * (1.0f / DMODEL);
    const float var = ss * (1.0f / DMODEL) - mu * mu;
    const float rs = rsqrtf(var + 1e-5f);
    OUT* orow = out + (size_t)row * DMODEL;
    orow[t]       = (OUT)((v0 - mu) * rs * g[t]       + bta[t]);
    orow[t + 256] = (OUT)((v1 - mu) * rs * g[t + 256] + bta[t + 256]);
    orow[t + 512] = (OUT)((v2 - mu) * rs * g[t + 512] + bta[t + 512]);
}

// ---------------- fused weight transpose+convert: all 6 weights, one launch ----------------
__global__ __launch_bounds__(256) void wtrans_all_kernel(
    const float* __restrict__ Wq, const float* __restrict__ Wk,
    const float* __restrict__ Wv, const float* __restrict__ Wo,
    const float* __restrict__ W1, const float* __restrict__ W2,
    bf16* __restrict__ Wqt, bf16* __restrict__ Wkt, bf16* __restrict__ Wvt,
    bf16* __restrict__ Wot, bf16* __restrict__ W1t, bf16* __restrict__ W2t) {
    int t = blockIdx.x;
    const float* W; bf16* Wt; int K, N;
    if      (t < 144)  { W = Wq; Wt = Wqt; K = 768;  N = 768;  }
    else if (t < 288)  { W = Wk; Wt = Wkt; K = 768;  N = 768;  t -= 144; }
    else if (t < 432)  { W = Wv; Wt = Wvt; K = 768;  N = 768;  t -= 288; }
    else if (t < 576)  { W = Wo; Wt = Wot; K = 768;  N = 768;  t -= 432; }
    else if (t < 1152) { W = W1; Wt = W1t; K = 768;  N = 3072; t -= 576; }
    else               { W = W2; Wt = W2t; K = 3072; N = 768;  t -= 1152; }
    const int nx = N >> 6;
    const int n0 = (t % nx) * 64, k0 = (t / nx) * 64;

    __shared__ float tile[64][65];
    const int tid = threadIdx.x;
    const int lr = tid >> 4, lc = (tid & 15) << 2;
#pragma unroll
    for (int i = 0; i < 4; ++i) {
        const int r = lr + i * 16;
        F4 w; w.v = *(const float4*)&W[(size_t)(k0 + r) * N + n0 + lc];
#pragma unroll
        for (int j = 0; j < 4; ++j) tile[r][lc + j] = w.f[j];
    }
    __syncthreads();
#pragma unroll
    for (int i = 0; i < 4; ++i) {
        const int n = lr + i * 16;
        bf16x4 o;
#pragma unroll
        for (int j = 0; j < 4; ++j) o[j] = (bf16)tile[lc + j][n];
        *(bf16x4*)&Wt[(size_t)(n0 + n) * K + k0 + lc] = o;
    }
}

// ---------------- bf16 MFMA GEMM, MT x 128 tile, BK=64 ----------------
template<int MT, bool RELU, bool RES, bool OUT_BF16>
__global__ __launch_bounds__(256) void mgemm_kernel(
    const bf16* __restrict__ A,
    const bf16* __restrict__ Wt0, const float* __restrict__ bias0, void* __restrict__ C0,
    const bf16* __restrict__ Wt1, const float* __restrict__ bias1, void* __restrict__ C1,
    const bf16* __restrict__ Wt2, const float* __restrict__ bias2, void* __restrict__ C2,
    const float* __restrict__ R, int M, int N, int K, int Kloop,
    int koff0, int koff1, int koff2,
    float sc0, float sc1, float sc2) {
    const bf16* Wt = Wt0; const float* bias = bias0; void* C = C0; float sc = sc0; int koff = koff0;
    if (blockIdx.z == 1) { Wt = Wt1; bias = bias1; C = C1; sc = sc1; koff = koff1; }
    if (blockIdx.z == 2) { Wt = Wt2; bias = bias2; C = C2; sc = sc2; koff = koff2; }

    constexpr int NI = (MT == 128) ? 4 : 2;
    __shared__ bf16 As[2][MT * 32];
    __shared__ bf16 Bs[2][128 * 32];

    const int tid = threadIdx.x;
    const int wave = tid >> 6, lane = tid & 63;
    const int row0 = blockIdx.y * MT, col0 = blockIdx.x * 128;
    const int wr = (MT == 128) ? (wave >> 1) * 64 : 0;
    const int wc = (MT == 128) ? (wave & 1) * 64 : wave * 32;
    const int mrow = lane & 15, kq = (lane >> 4) * 8;

    const int st_row = (lane >> 2);
    const int st_off = (lane & 3) * 16;

    f32x4 acc[4][NI] = {};

    const char* Ab = (const char*)(A + (size_t)row0 * K + koff);
    const char* Bb = (const char*)(Wt + (size_t)col0 * K + koff);
    const size_t strideA = (size_t)K * 2;

    for (int k0 = 0; k0 < Kloop; k0 += 64) {
#pragma unroll
        for (int s = 0; s < 2; ++s) {
            const int kk = k0 + s * 32;
            if (MT == 128) {
#pragma unroll
                for (int issue = 0; issue < 2; ++issue) {
                    const int r = wave * 32 + issue * 16 + st_row;
                    gld_lds16((char*)As[s] + (wave * 32 + issue * 16) * 64,
                              Ab + (size_t)r * strideA + kk * 2 + st_off);
                }
            } else {
                const int r = wave * 16 + st_row;
                gld_lds16((char*)As[s] + (wave * 16) * 64,
                          Ab + (size_t)r * strideA + kk * 2 + st_off);
            }
#pragma unroll
            for (int issue = 0; issue < 2; ++issue) {
                const int r = wave * 32 + issue * 16 + st_row;
                gld_lds16((char*)Bs[s] + (wave * 32 + issue * 16) * 64,
                          Bb + (size_t)r * strideA + kk * 2 + st_off);
            }
        }
        __syncthreads();
#pragma unroll
        for (int s = 0; s < 2; ++s) {
            bf16x8 af[4], bfr[NI];
#pragma unroll
            for (int mi = 0; mi < 4; ++mi)
                af[mi] = *(const bf16x8*)&As[s][(wr + mi * 16 + mrow) * 32 + kq];
#pragma unroll
            for (int ni = 0; ni < NI; ++ni)
                bfr[ni] = *(const bf16x8*)&Bs[s][(wc + ni * 16 + mrow) * 32 + kq];
#pragma unroll
            for (int mi = 0; mi < 4; ++mi)
#pragma unroll
                for (int ni = 0; ni < NI; ++ni)
                    acc[mi][ni] = __builtin_amdgcn_mfma_f32_16x16x32_bf16(
                        af[mi], bfr[ni], acc[mi][ni], 0, 0, 0);
        }
        __syncthreads();
    }

    const int quad = lane >> 4;
    float bv[NI];
#pragma unroll
    for (int ni = 0; ni < NI; ++ni) bv[ni] = bias[col0 + wc + ni * 16 + mrow];
#pragma unroll
    for (int mi = 0; mi < 4; ++mi) {
#pragma unroll
        for (int r = 0; r < 4; ++r) {
            const int row = row0 + wr + mi * 16 + quad * 4 + r;
#pragma unroll
            for (int ni = 0; ni < NI; ++ni) {
                const int col = col0 + wc + ni * 16 + mrow;
                float v = acc[mi][ni][r] + bv[ni];
                if (RES) v += R[(size_t)row * N + col];
                v *= sc;
                if (RELU) v = fmaxf(v, 0.0f);
                if (OUT_BF16) ((bf16*)C)[(size_t)row * N + col] = (bf16)v;
                else          ((float*)C)[(size_t)row * N + col] = v;
            }
        }
    }
}

// ---------------- FF2 split-K combine: out = p0 + p1 + b2 + x1 ----------------
__global__ __launch_bounds__(256) void ff2_combine_kernel(
    const bf16* __restrict__ p0, const bf16* __restrict__ p1,
    const float* __restrict__ b2, const float* __restrict__ x1,
    float* __restrict__ out) {
    const int i = (blockIdx.x * 256 + threadIdx.x) * 4;
    bf16x4 a = *(const bf16x4*)(p0 + i);
    bf16x4 b = *(const bf16x4*)(p1 + i);
    F4 xr; xr.v = *(const float4*)(x1 + i);
    const int col = i % DMODEL;
    F4 o;
#pragma unroll
    for (int j = 0; j < 4; ++j)
        o.f[j] = (float)a[j] + (float)b[j] + b2[col + j] + xr.f[j];
    *(float4*)(out + i) = o.v;
}

// ---------------- Transposed-S MFMA flash attention (shfl-free PV + MFMA-fused l) ----------------
// S^T = K·Q^T. PV uses 16x16x16 MFMA (B-layout == S^T C-layout: no shfl).
// Row-sum l fused into PV via a CONSTANT all-ones A-fragment (no LDS ones row).
// LDS trimmed to ~35 KB (epilogue bounce aliases Ks[0]) -> 4 blocks/CU.
// grid (64,H,B) = 1536 single-tile blocks, big qt dispatched first for balance.
// Double-buffered K/V, 1 barrier/iter; T13 defer-max gates the alpha rescale;
// T5 setprio(1) around both MFMA clusters.
__global__ __launch_bounds__(256) void mattn_kernel(
    const bf16* __restrict__ Q, const bf16* __restrict__ K,
    const bf16* __restrict__ V, const int* __restrict__ amask,
    bf16* __restrict__ O) {
    const int qt = 63 - blockIdx.x;   // big tiles dispatch first
    const int h = blockIdx.y, b = blockIdx.z;

    __shared__ bf16 Ks[2][64][68];   // [buf][key][d]  (136 B rows: conflict-free)
    __shared__ bf16 Vt[2][64][68];   // [buf][d][key]
    __shared__ float mk[2][64];
    __shared__ int flagv[2];

    const int tid = threadIdx.x;
    const int wave = tid >> 6, lane = tid & 63;
    const int l = lane & 15, quad = lane >> 4;
#if !HAVE_MFMA16
    const int qh = quad >> 1;
    const int srcA = (quad & 1) * 32 + l;
    const int srcB = srcA + 16;
#endif
    const float NEG_INF = -__builtin_huge_valf();

    const int kr = tid >> 2, ks = (tid & 3) * 16;          // K tile staging
    const int vk0 = (tid & 31) * 2, vds = (tid >> 5) * 8;  // V transpose staging

    const bf16* Kbase = K + (size_t)b * S_LEN * DMODEL + h * HDIM;
    const bf16* Vbase = V + (size_t)b * S_LEN * DMODEL + h * HDIM;

#if HAVE_MFMA16
    U4 onesf;                       // constant all-ones A fragment for l-fusion
    onesf.u[0] = 0x3F803F80u; onesf.u[1] = 0x3F803F80u;
#endif

    const bf16* Qb = Q + (size_t)(b * S_LEN + qt * 64 + wave * 16 + l) * DMODEL + h * HDIM;
    const bf16x8 qf0 = *(const bf16x8*)(Qb + quad * 8);
    const bf16x8 qf1 = *(const bf16x8*)(Qb + 32 + quad * 8);

    float m_run = NEG_INF;
#if !HAVE_MFMA16
    float l_run = 0.0f;
#endif
    f32x4 acc[4] = {};
#if HAVE_MFMA16
    f32x4 acc_l = {};   // D-row 0 (quad-0 lanes, elem 0) accumulates l
#endif

    // ---- prefetch + stage tile 0 ----
    bf16x8 kp0, kp1, vp0, vp1;
    int mv = 1;
    {
        const bf16* kg = Kbase + (size_t)kr * DMODEL + ks;
        kp0 = *(const bf16x8*)kg;
        kp1 = *(const bf16x8*)(kg + 8);
        const bf16* vg = Vbase + (size_t)vk0 * DMODEL + vds;
        vp0 = *(const bf16x8*)vg;
        vp1 = *(const bf16x8*)(vg + DMODEL);
        if (wave == 0) mv = amask[b * S_LEN + lane];
        *(bf16x8*)&Ks[0][kr][ks]     = kp0;
        *(bf16x8*)&Ks[0][kr][ks + 8] = kp1;
#pragma unroll
        for (int i = 0; i < 8; ++i) {
            U2 w; w.h[0] = vp0[i]; w.h[1] = vp1[i];
            *(unsigned*)&Vt[0][vds + i][vk0] = w.u;
        }
        if (wave == 0) {
            mk[0][lane] = mv ? 0.0f : NEG_INF;
            unsigned long long bal = __ballot(mv != 0);
            if (lane == 0) flagv[0] = (bal == ~0ULL);
        }
    }
    __syncthreads();
    int buf = 0;

    for (int kt = 0; kt <= qt; ++kt) {
        const bool more = (kt < qt);
        if (more) {
            const bf16* kg = Kbase + (size_t)((kt + 1) * 64 + kr) * DMODEL + ks;
            kp0 = *(const bf16x8*)kg;
            kp1 = *(const bf16x8*)(kg + 8);
            const bf16* vg = Vbase + (size_t)((kt + 1) * 64 + vk0) * DMODEL + vds;
            vp0 = *(const bf16x8*)vg;
            vp1 = *(const bf16x8*)(vg + DMODEL);
            if (wave == 0) mv = amask[b * S_LEN + (kt + 1) * 64 + lane];
        }

        const int allv = flagv[buf];
        f32x4 sreg[4] = {};
        __builtin_amdgcn_s_setprio(1);
#pragma unroll
        for (int mi = 0; mi < 4; ++mi) {
            bf16x8 kf0 = *(const bf16x8*)&Ks[buf][mi * 16 + l][quad * 8];
            bf16x8 kf1 = *(const bf16x8*)&Ks[buf][mi * 16 + l][32 + quad * 8];
            sreg[mi] = __builtin_amdgcn_mfma_f32_16x16x32_bf16(kf0, qf0, sreg[mi], 0, 0, 0);
            sreg[mi] = __builtin_amdgcn_mfma_f32_16x16x32_bf16(kf1, qf1, sreg[mi], 0, 0, 0);
        }
        __builtin_amdgcn_s_setprio(0);
        if (!allv) {
#pragma unroll
            for (int mi = 0; mi < 4; ++mi) {
                F4 m4; m4.v = *(const float4*)&mk[buf][mi * 16 + quad * 4];
#pragma unroll
                for (int r = 0; r < 4; ++r) sreg[mi][r] += m4.f[r];
            }
        }
        if (kt == qt) {
#pragma unroll
            for (int mi = 0; mi < 4; ++mi)
#pragma unroll
                for (int r = 0; r < 4; ++r)
                    if (mi * 16 + quad * 4 + r > wave * 16 + l)
                        sreg[mi][r] = NEG_INF;
        }

        // online softmax: max-reduce (15 max + 2 shfl); T13 defer-max gates rescale.
        float mloc = sreg[0][0];
#pragma unroll
        for (int mi = 0; mi < 4; ++mi)
#pragma unroll
            for (int r = 0; r < 4; ++r) mloc = fmaxf(mloc, sreg[mi][r]);
        mloc = fmaxf(mloc, __shfl_xor(mloc, 16, 64));
        mloc = fmaxf(mloc, __shfl_xor(mloc, 32, 64));
        if (__any(mloc > m_run + 8.0f)) {
            const float mn = fmaxf(m_run, mloc);
            const float alpha = __builtin_amdgcn_exp2f(m_run - mn);
            m_run = mn;
#pragma unroll
            for (int mi = 0; mi < 4; ++mi)
#pragma unroll
                for (int r = 0; r < 4; ++r) acc[mi][r] *= alpha;
#if HAVE_MFMA16
#pragma unroll
            for (int r = 0; r < 4; ++r) acc_l[r] *= alpha;
#else
            l_run *= alpha;
#endif
        }
#pragma unroll
        for (int mi = 0; mi < 4; ++mi)
#pragma unroll
            for (int r = 0; r < 4; ++r)
                sreg[mi][r] = __builtin_amdgcn_exp2f(sreg[mi][r] - m_run);
#if !HAVE_MFMA16
        float ls = 0.0f;
#pragma unroll
        for (int mi = 0; mi < 4; ++mi)
#pragma unroll
            for (int r = 0; r < 4; ++r) ls += sreg[mi][r];
        ls += __shfl_xor(ls, 16, 64);
        ls += __shfl_xor(ls, 32, 64);
        l_run += ls;
#endif

        // pack P^T to bf16 dwords (keys mi*16+quad*4+{0..3}, query l)
        unsigned pk[4][2];
#pragma unroll
        for (int mi = 0; mi < 4; ++mi) {
            U2 w0; w0.h[0] = (bf16)sreg[mi][0]; w0.h[1] = (bf16)sreg[mi][1];
            U2 w1; w1.h[0] = (bf16)sreg[mi][2]; w1.h[1] = (bf16)sreg[mi][3];
            pk[mi][0] = w0.u; pk[mi][1] = w1.u;
        }

#if HAVE_MFMA16
        // O^T += V^T · P^T ; extra MFMA with constant ones-A accumulates l.
        __builtin_amdgcn_s_setprio(1);
#pragma unroll
        for (int mi = 0; mi < 4; ++mi) {
            U4 pb; pb.u[0] = pk[mi][0]; pb.u[1] = pk[mi][1];
#pragma unroll
            for (int di = 0; di < 4; ++di) {
                mf16_t va = *(const mf16_t*)&Vt[buf][di * 16 + l][mi * 16 + quad * 4];
                acc[di] = MFMA16(va, pb.v, acc[di]);
            }
            acc_l = MFMA16(onesf.v, pb.v, acc_l);
        }
        __builtin_amdgcn_s_setprio(0);
#else
        bf16x8 pfrag[2];
#pragma unroll
        for (int kc = 0; kc < 2; ++kc) {
            U8 u;
#pragma unroll
            for (int t = 0; t < 2; ++t) {
                const unsigned a0 = (unsigned)__shfl((int)pk[2 * kc][t],     srcA, 64);
                const unsigned b0 = (unsigned)__shfl((int)pk[2 * kc + 1][t], srcA, 64);
                u.u[t] = qh ? b0 : a0;
                const unsigned a1 = (unsigned)__shfl((int)pk[2 * kc][t],     srcB, 64);
                const unsigned b1 = (unsigned)__shfl((int)pk[2 * kc + 1][t], srcB, 64);
                u.u[2 + t] = qh ? b1 : a1;
            }
            pfrag[kc] = u.v;
        }
#pragma unroll
        for (int mi = 0; mi < 4; ++mi) {
            bf16x8 vf0 = *(const bf16x8*)&Vt[buf][mi * 16 + l][quad * 8];
            bf16x8 vf1 = *(const bf16x8*)&Vt[buf][mi * 16 + l][32 + quad * 8];
            acc[mi] = __builtin_amdgcn_mfma_f32_16x16x32_bf16(vf0, pfrag[0], acc[mi], 0, 0, 0);
            acc[mi] = __builtin_amdgcn_mfma_f32_16x16x32_bf16(vf1, pfrag[1], acc[mi], 0, 0, 0);
        }
#endif

        if (more) {
            const int nb = buf ^ 1;
            *(bf16x8*)&Ks[nb][kr][ks]     = kp0;
            *(bf16x8*)&Ks[nb][kr][ks + 8] = kp1;
#pragma unroll
            for (int i = 0; i < 8; ++i) {
                U2 w; w.h[0] = vp0[i]; w.h[1] = vp1[i];
                *(unsigned*)&Vt[nb][vds + i][vk0] = w.u;
            }
            if (wave == 0) {
                mk[nb][lane] = mv ? 0.0f : NEG_INF;
                unsigned long long bal = __ballot(mv != 0);
                if (lane == 0) flagv[nb] = (bal == ~0ULL);
            }
        }
        __syncthreads();
        buf ^= 1;
    }

#if HAVE_MFMA16
    // l lives in acc_l[0] of quad-0 lane with col==query; broadcast via shfl.
    const float l_fin = __shfl(acc_l[0], l, 64);
#else
    const float l_fin = l_run;
#endif
    const float rinv = 1.0f / l_fin;
    // epilogue bounce reuses Ks[0] (dead after the loop-ending barrier)
    bf16 (*Os)[68] = (bf16 (*)[68])(&Ks[0][0][0]);
#pragma unroll
    for (int mi = 0; mi < 4; ++mi) {
        U2 w0; w0.h[0] = (bf16)(acc[mi][0] * rinv); w0.h[1] = (bf16)(acc[mi][1] * rinv);
        U2 w1; w1.h[0] = (bf16)(acc[mi][2] * rinv); w1.h[1] = (bf16)(acc[mi][3] * rinv);
        *(unsigned*)&Os[wave * 16 + l][mi * 16 + quad * 4]     = w0.u;
        *(unsigned*)&Os[wave * 16 + l][mi * 16 + quad * 4 + 2] = w1.u;
    }
    __syncthreads();
    {
        const int orow = tid >> 2, oseg = (tid & 3) * 16;
        bf16* Og = O + (size_t)(b * S_LEN + qt * 64 + orow) * DMODEL + h * HDIM + oseg;
        *(bf16x8*)Og       = *(const bf16x8*)&Os[orow][oseg];
        *(bf16x8*)(Og + 8) = *(const bf16x8*)&Os[orow][oseg + 8];
    }
}

// ---------------- launcher ----------------
extern "C" void kernel_launch(void* const* d_in, const int* in_sizes, int n_in,
                              void* d_out, int out_size, void* d_ws, size_t ws_size,
                              hipStream_t stream) {
    const float* x     = (const float*)d_in[0];
    const int*   amask = (const int*)  d_in[1];
    const float* ln1_g = (const float*)d_in[2];
    const float* ln1_b = (const float*)d_in[3];
    const float* ln2_g = (const float*)d_in[4];
    const float* ln2_b = (const float*)d_in[5];
    const float* Wq = (const float*)d_in[6];  const float* bq = (const float*)d_in[7];
    const float* Wk = (const float*)d_in[8];  const float* bk = (const float*)d_in[9];
    const float* Wv = (const float*)d_in[10]; const float* bv = (const float*)d_in[11];
    const float* Wo = (const float*)d_in[12]; const float* bo = (const float*)d_in[13];
    const float* W1 = (const float*)d_in[14]; const float* b1 = (const float*)d_in[15];
    const float* W2 = (const float*)d_in[16]; const float* b2 = (const float*)d_in[17];
    float* out = (float*)d_out;

    char* ws = (char*)d_ws;
    const size_t WSML = (size_t)DMODEL * DMODEL * 2;
    const size_t WBIG = (size_t)DMODEL * DFF_ * 2;
    bf16* Wqt = (bf16*)(ws + 0 * WSML);
    bf16* Wkt = (bf16*)(ws + 1 * WSML);
    bf16* Wvt = (bf16*)(ws + 2 * WSML);
    bf16* Wot = (bf16*)(ws + 3 * WSML);
    bf16* W1t = (bf16*)(ws + 4 * WSML);
    bf16* W2t = (bf16*)(ws + 4 * WSML + WBIG);
    char* act = ws + 4 * WSML + 2 * WBIG;

    const size_t HB = (size_t)MROWS * DMODEL * 2;   // bf16 activation (12.6 MB)
    const size_t FB = (size_t)MROWS * DMODEL * 4;   // fp32 activation (25.2 MB)
    bf16*  h    = (bf16*)(act);            // LN1 out; later ctx; later h2
    bf16*  qb   = (bf16*)(act + HB);
    bf16*  kb   = (bf16*)(act + 2 * HB);
    bf16*  vb   = (bf16*)(act + 3 * HB);
    bf16*  ctx  = h;
    float* x1   = (float*)(act + 4 * HB);
    bf16*  f    = (bf16*)(act + 4 * HB + FB);      // FF1 out (50.3 MB)
    bf16*  h2   = h;
    bf16*  p0   = qb;                               // FF2 split-K partials
    bf16*  p1   = kb;
    float* zbias = (float*)vb;                      // zero bias; re-zeroed at LN2
                                                    // (vb dead after attention)

    const float SCL = 0.125f * 1.44269504089f;  // 1/sqrt(64) * log2(e), folded into Q

    // 0. fused weight transpose+convert (one launch, 1728 tiles)
    wtrans_all_kernel<<<1728, 256, 0, stream>>>(Wq, Wk, Wv, Wo, W1, W2,
                                                Wqt, Wkt, Wvt, Wot, W1t, W2t);

    // 1. LN1 -> h (bf16)
    ln_kernel<bf16><<<MROWS, 256, 0, stream>>>(x, ln1_g, ln1_b, h, nullptr);
    // 2. QKV fused, bf16 out; Q pre-scaled by SCL  (1152 blocks)
    mgemm_kernel<128, false, false, true><<<dim3(DMODEL / 128, MROWS / 128, 3), 256, 0, stream>>>(
        h, Wqt, bq, qb, Wkt, bk, kb, Wvt, bv, vb, nullptr,
        MROWS, DMODEL, DMODEL, DMODEL, 0, 0, 0, SCL, 1.0f, 1.0f);
    // 3. flash attention -> ctx (bf16)  (1536 single-tile blocks, 4/CU resident)
    mattn_kernel<<<dim3(64, NHEAD, 2), 256, 0, stream>>>(qb, kb, vb, amask, ctx);
    // 4. out proj + residual(x) -> x1 (fp32)  (MT=64: 768 blocks)
    mgemm_kernel<64, false, true, false><<<dim3(DMODEL / 128, MROWS / 64, 1), 256, 0, stream>>>(
        ctx, Wot, bo, x1, Wot, bo, x1, Wot, bo, x1, x,
        MROWS, DMODEL, DMODEL, DMODEL, 0, 0, 0, 1.0f, 1.0f, 1.0f);
    // 5. LN2 -> h2 (bf16) + zero zbias (vb dead now, before FF2 reads it)
    ln_kernel<bf16><<<MROWS, 256, 0, stream>>>(x1, ln2_g, ln2_b, h2, zbias);
    // 6. FF1 + relu -> f (bf16)  (1536 blocks)
    mgemm_kernel<128, true, false, true><<<dim3(DFF_ / 128, MROWS / 128, 1), 256, 0, stream>>>(
        h2, W1t, b1, f, W1t, b1, f, W1t, b1, f, nullptr,
        MROWS, DFF_, DMODEL, DMODEL, 0, 0, 0, 1.0f, 1.0f, 1.0f);
    // 7. FF2 split-K: z=0 -> K[0,1536) into p0; z=1 -> K[1536,3072) into p1
    mgemm_kernel<128, false, false, true><<<dim3(DMODEL / 128, MROWS / 128, 2), 256, 0, stream>>>(
        f, W2t, zbias, p0, W2t, zbias, p1, W2t, zbias, p1, nullptr,
        MROWS, DMODEL, DFF_, DFF_ / 2, 0, DFF_ / 2, 0, 1.0f, 1.0f, 1.0f);
    // 7b. combine: out = p0 + p1 + b2 + x1  (6144 blocks)
    ff2_combine_kernel<<<(MROWS * DMODEL) / 1024, 256, 0, stream>>>(p0, p1, b2, x1, out);
}

// Round 3
// 484.226 us; speedup vs baseline: 1.0709x; 1.0709x over previous
//
#include <hip/hip_runtime.h>
#include <hip/hip_bf16.h>
#include <math.h>

#define S_LEN 4096
#define DMODEL 768
#define NHEAD 12
#define HDIM 64
#define DFF_ 3072
#define MROWS 8192  // B*S

typedef __bf16 bf16;
typedef __bf16 bf16x4 __attribute__((ext_vector_type(4)));
typedef __bf16 bf16x8 __attribute__((ext_vector_type(8)));
typedef float f32x4 __attribute__((ext_vector_type(4)));
typedef short s16x4 __attribute__((ext_vector_type(4)));
typedef s16x4 frag4;

union F4 { float4 v; float f[4]; };

__device__ __forceinline__ void gld_lds16(void* lds, const void* g) {
    __builtin_amdgcn_global_load_lds(
        (const __attribute__((address_space(1))) unsigned int*)g,
        (__attribute__((address_space(3))) unsigned int*)lds, 16, 0, 0);
}

__device__ __forceinline__ unsigned lds_off(const void* p) {
    return (unsigned)(size_t)(const __attribute__((address_space(3))) char*)p;
}

// 16x16x16 bf16 MFMA. A layout: lane holds A[row=lane&15][k=(lane>>4)*4+j];
// B layout: B[k=(lane>>4)*4+j][n=lane&15]; C: D[row=(lane>>4)*4+r][col=lane&15].
__device__ __forceinline__ f32x4 mfma16(frag4 a, frag4 b, f32x4 c) {
#if __has_builtin(__builtin_amdgcn_mfma_f32_16x16x16bf16_1k)
    return __builtin_amdgcn_mfma_f32_16x16x16bf16_1k(a, b, c, 0, 0, 0);
#else
    // zero-padded 16x16x32 fallback: k = quad*8 + j with upper 4 zeros on both
    // operands hits the same nonzero k-slots -> identical result.
    union { frag4 s; bf16x4 h; } ua, ub; ua.s = a; ub.s = b;
    bf16x8 a8 = {ua.h[0], ua.h[1], ua.h[2], ua.h[3],
                 (bf16)0.f, (bf16)0.f, (bf16)0.f, (bf16)0.f};
    bf16x8 b8 = {ub.h[0], ub.h[1], ub.h[2], ub.h[3],
                 (bf16)0.f, (bf16)0.f, (bf16)0.f, (bf16)0.f};
    return __builtin_amdgcn_mfma_f32_16x16x32_bf16(a8, b8, c, 0, 0, 0);
#endif
}

// ---------------- LayerNorm (optionally zero-fills the 768-float zbias buf) ----------------
template<typename OUT>
__global__ __launch_bounds__(256) void ln_kernel(const float* __restrict__ x,
                                                 const float* __restrict__ g,
                                                 const float* __restrict__ bta,
                                                 OUT* __restrict__ out,
                                                 float* __restrict__ zb) {
    const int row = blockIdx.x;
    const int t = threadIdx.x;
    if (zb && row == 0 && t < 192)
        ((float4*)zb)[t] = make_float4(0.f, 0.f, 0.f, 0.f);
    const float* xr = x + (size_t)row * DMODEL;
    float v0 = xr[t], v1 = xr[t + 256], v2 = xr[t + 512];
    float s = v0 + v1 + v2;
    float ss = v0 * v0 + v1 * v1 + v2 * v2;
    for (int o = 32; o > 0; o >>= 1) {
        s += __shfl_down(s, o, 64);
        ss += __shfl_down(ss, o, 64);
    }
    __shared__ float sm[4], sm2[4];
    const int w = t >> 6, lane = t & 63;
    if (lane == 0) { sm[w] = s; sm2[w] = ss; }
    __syncthreads();
    s = sm[0] + sm[1] + sm[2] + sm[3];
    ss = sm2[0] + sm2[1] + sm2[2] + sm2[3];
    const float mu = s * (1.0f / DMODEL);
    const float var = ss * (1.0f / DMODEL) - mu * mu;
    const float rs = rsqrtf(var + 1e-5f);
    OUT* orow = out + (size_t)row * DMODEL;
    orow[t]       = (OUT)((v0 - mu) * rs * g[t]       + bta[t]);
    orow[t + 256] = (OUT)((v1 - mu) * rs * g[t + 256] + bta[t + 256]);
    orow[t + 512] = (OUT)((v2 - mu) * rs * g[t + 512] + bta[t + 512]);
}

// ---------------- fused weight transpose+convert: all 6 weights, one launch ----------------
__global__ __launch_bounds__(256) void wtrans_all_kernel(
    const float* __restrict__ Wq, const float* __restrict__ Wk,
    const float* __restrict__ Wv, const float* __restrict__ Wo,
    const float* __restrict__ W1, const float* __restrict__ W2,
    bf16* __restrict__ Wqt, bf16* __restrict__ Wkt, bf16* __restrict__ Wvt,
    bf16* __restrict__ Wot, bf16* __restrict__ W1t, bf16* __restrict__ W2t) {
    int t = blockIdx.x;
    const float* W; bf16* Wt; int K, N;
    if      (t < 144)  { W = Wq; Wt = Wqt; K = 768;  N = 768;  }
    else if (t < 288)  { W = Wk; Wt = Wkt; K = 768;  N = 768;  t -= 144; }
    else if (t < 432)  { W = Wv; Wt = Wvt; K = 768;  N = 768;  t -= 288; }
    else if (t < 576)  { W = Wo; Wt = Wot; K = 768;  N = 768;  t -= 432; }
    else if (t < 1152) { W = W1; Wt = W1t; K = 768;  N = 3072; t -= 576; }
    else               { W = W2; Wt = W2t; K = 3072; N = 768;  t -= 1152; }
    const int nx = N >> 6;
    const int n0 = (t % nx) * 64, k0 = (t / nx) * 64;

    __shared__ float tile[64][65];
    const int tid = threadIdx.x;
    const int lr = tid >> 4, lc = (tid & 15) << 2;
#pragma unroll
    for (int i = 0; i < 4; ++i) {
        const int r = lr + i * 16;
        F4 w; w.v = *(const float4*)&W[(size_t)(k0 + r) * N + n0 + lc];
#pragma unroll
        for (int j = 0; j < 4; ++j) tile[r][lc + j] = w.f[j];
    }
    __syncthreads();
#pragma unroll
    for (int i = 0; i < 4; ++i) {
        const int n = lr + i * 16;
        bf16x4 o;
#pragma unroll
        for (int j = 0; j < 4; ++j) o[j] = (bf16)tile[lc + j][n];
        *(bf16x4*)&Wt[(size_t)(n0 + n) * K + k0 + lc] = o;
    }
}

// ---------------- bf16 MFMA GEMM, MT x 128 tile, BK=64 ----------------
template<int MT, bool RELU, bool RES, bool OUT_BF16>
__global__ __launch_bounds__(256) void mgemm_kernel(
    const bf16* __restrict__ A,
    const bf16* __restrict__ Wt0, const float* __restrict__ bias0, void* __restrict__ C0,
    const bf16* __restrict__ Wt1, const float* __restrict__ bias1, void* __restrict__ C1,
    const bf16* __restrict__ Wt2, const float* __restrict__ bias2, void* __restrict__ C2,
    const float* __restrict__ R, int M, int N, int K, int Kloop,
    int koff0, int koff1, int koff2,
    float sc0, float sc1, float sc2) {
    const bf16* Wt = Wt0; const float* bias = bias0; void* C = C0; float sc = sc0; int koff = koff0;
    if (blockIdx.z == 1) { Wt = Wt1; bias = bias1; C = C1; sc = sc1; koff = koff1; }
    if (blockIdx.z == 2) { Wt = Wt2; bias = bias2; C = C2; sc = sc2; koff = koff2; }

    constexpr int NI = (MT == 128) ? 4 : 2;
    __shared__ bf16 As[2][MT * 32];
    __shared__ bf16 Bs[2][128 * 32];

    const int tid = threadIdx.x;
    const int wave = tid >> 6, lane = tid & 63;
    const int row0 = blockIdx.y * MT, col0 = blockIdx.x * 128;
    const int wr = (MT == 128) ? (wave >> 1) * 64 : 0;
    const int wc = (MT == 128) ? (wave & 1) * 64 : wave * 32;
    const int mrow = lane & 15, kq = (lane >> 4) * 8;

    const int st_row = (lane >> 2);
    const int st_off = (lane & 3) * 16;

    f32x4 acc[4][NI] = {};

    const char* Ab = (const char*)(A + (size_t)row0 * K + koff);
    const char* Bb = (const char*)(Wt + (size_t)col0 * K + koff);
    const size_t strideA = (size_t)K * 2;

    for (int k0 = 0; k0 < Kloop; k0 += 64) {
#pragma unroll
        for (int s = 0; s < 2; ++s) {
            const int kk = k0 + s * 32;
            if (MT == 128) {
#pragma unroll
                for (int issue = 0; issue < 2; ++issue) {
                    const int r = wave * 32 + issue * 16 + st_row;
                    gld_lds16((char*)As[s] + (wave * 32 + issue * 16) * 64,
                              Ab + (size_t)r * strideA + kk * 2 + st_off);
                }
            } else {
                const int r = wave * 16 + st_row;
                gld_lds16((char*)As[s] + (wave * 16) * 64,
                          Ab + (size_t)r * strideA + kk * 2 + st_off);
            }
#pragma unroll
            for (int issue = 0; issue < 2; ++issue) {
                const int r = wave * 32 + issue * 16 + st_row;
                gld_lds16((char*)Bs[s] + (wave * 32 + issue * 16) * 64,
                          Bb + (size_t)r * strideA + kk * 2 + st_off);
            }
        }
        __syncthreads();
#pragma unroll
        for (int s = 0; s < 2; ++s) {
            bf16x8 af[4], bfr[NI];
#pragma unroll
            for (int mi = 0; mi < 4; ++mi)
                af[mi] = *(const bf16x8*)&As[s][(wr + mi * 16 + mrow) * 32 + kq];
#pragma unroll
            for (int ni = 0; ni < NI; ++ni)
                bfr[ni] = *(const bf16x8*)&Bs[s][(wc + ni * 16 + mrow) * 32 + kq];
#pragma unroll
            for (int mi = 0; mi < 4; ++mi)
#pragma unroll
                for (int ni = 0; ni < NI; ++ni)
                    acc[mi][ni] = __builtin_amdgcn_mfma_f32_16x16x32_bf16(
                        af[mi], bfr[ni], acc[mi][ni], 0, 0, 0);
        }
        __syncthreads();
    }

    const int quad = lane >> 4;
    float bv[NI];
#pragma unroll
    for (int ni = 0; ni < NI; ++ni) bv[ni] = bias[col0 + wc + ni * 16 + mrow];
#pragma unroll
    for (int mi = 0; mi < 4; ++mi) {
#pragma unroll
        for (int r = 0; r < 4; ++r) {
            const int row = row0 + wr + mi * 16 + quad * 4 + r;
#pragma unroll
            for (int ni = 0; ni < NI; ++ni) {
                const int col = col0 + wc + ni * 16 + mrow;
                float v = acc[mi][ni][r] + bv[ni];
                if (RES) v += R[(size_t)row * N + col];
                v *= sc;
                if (RELU) v = fmaxf(v, 0.0f);
                if (OUT_BF16) ((bf16*)C)[(size_t)row * N + col] = (bf16)v;
                else          ((float*)C)[(size_t)row * N + col] = v;
            }
        }
    }
}

// ---------------- FF2 split-K combine: out = p0 + p1 + b2 + x1 ----------------
__global__ __launch_bounds__(256) void ff2_combine_kernel(
    const bf16* __restrict__ p0, const bf16* __restrict__ p1,
    const float* __restrict__ b2, const float* __restrict__ x1,
    float* __restrict__ out) {
    const int i = (blockIdx.x * 256 + threadIdx.x) * 4;
    bf16x4 a = *(const bf16x4*)(p0 + i);
    bf16x4 b = *(const bf16x4*)(p1 + i);
    F4 xr; xr.v = *(const float4*)(x1 + i);
    const int col = i % DMODEL;
    F4 o;
#pragma unroll
    for (int j = 0; j < 4; ++j)
        o.f[j] = (float)a[j] + (float)b[j] + b2[col + j] + xr.f[j];
    *(float4*)(out + i) = o.v;
}

// ---------------- Transposed-S MFMA flash attention, O = P·V via tr-read V ----------------
// S^T = K·Q^T (sreg: query=l, key=quad*4+r). PV flipped to O = P·V:
//   A = P straight from the softmax'd sreg pack (S^T C-layout == A-layout),
//   B = V fragments via ds_read_b64_tr_b16 from row-major 16x16 bf16 subtiles.
// tr-read semantics (m162): NO internal lane offset; per-lane addr = base+lane*8B
// makes the wave cover exactly one 512B subtile, and the transpose network gives
// lane l elem j = subtile[key=(l>>4)*4+j][d=l&15] == the 16x16x16 B fragment.
// offset:i*512 walks the 16 subtiles (s = mi*4+di).
// V staging is 2x global_load_lds per thread: NO transpose pack, NO ds_writes.
// Row-sum l fused via constant all-ones B fragment; acc rows are query-major so
// 1/l applies in-lane. Defer-max (T13) gates the alpha rescale (4 gated shfls).
// grid (32,H,B) = 768 paired-uniform blocks (load-balance optimal: r1 lesson);
// double-buffered K/V, 1 barrier/iter, setprio (T5) around MFMA clusters.
__global__ __launch_bounds__(256) void mattn_kernel(
    const bf16* __restrict__ Q, const bf16* __restrict__ K,
    const bf16* __restrict__ V, const int* __restrict__ amask,
    bf16* __restrict__ O) {
    const int bx = blockIdx.x, h = blockIdx.y, b = blockIdx.z;

    __shared__ bf16 Ks[2][64][68];   // [buf][key][d] (136 B rows: conflict-free)
    __shared__ bf16 Vs[2][4096];     // [buf] 16 subtiles x (16 key x 16 d), 8 KB
    __shared__ float mk[2][64];
    __shared__ int flagv[2];

    const int tid = threadIdx.x;
    const int wave = tid >> 6, lane = tid & 63;
    const int l = lane & 15, quad = lane >> 4;
    const float NEG_INF = -__builtin_huge_valf();

    const int kr = tid >> 2, ks = (tid & 3) * 16;   // K tile staging

    const bf16* Kbase = K + (size_t)b * S_LEN * DMODEL + h * HDIM;
    const bf16* Vbase = V + (size_t)b * S_LEN * DMODEL + h * HDIM;

    // V DMA granule g = e*256 + tid: subtile s=g>>5 (mi=s>>2, di=s&3),
    // key-row r=(g>>1)&15, half hf=g&1. LDS dest byte = 16*g (linear: gld_lds
    // writes wave-uniform base + lane*16). Source = V[mi*16+r][di*16+hf*8 ..+8).
    int voff0, voff1;
    {
        const int g0 = tid, s0 = g0 >> 5;
        voff0 = ((s0 >> 2) * 16 + ((g0 >> 1) & 15)) * DMODEL + (s0 & 3) * 16 + (g0 & 1) * 8;
        const int g1 = 256 + tid, s1 = g1 >> 5;
        voff1 = ((s1 >> 2) * 16 + ((g1 >> 1) & 15)) * DMODEL + (s1 & 3) * 16 + (g1 & 1) * 8;
    }
    const int vdst0 = (wave * 64) * 16;
    const int vdst1 = (256 + wave * 64) * 16;

    const frag4 onesf = {(short)0x3F80, (short)0x3F80, (short)0x3F80, (short)0x3F80};
    // per-lane tr-read base: lane*8 bytes (wave covers one 512B subtile).
    const unsigned vtr0 = lds_off(&Vs[0][0]) + lane * 8;

#pragma unroll 1
    for (int pass = 0; pass < 2; ++pass) {
        const int qt = pass ? bx : (63 - bx);

        const bf16* Qb = Q + (size_t)(b * S_LEN + qt * 64 + wave * 16 + l) * DMODEL + h * HDIM;
        const bf16x8 qf0 = *(const bf16x8*)(Qb + quad * 8);
        const bf16x8 qf1 = *(const bf16x8*)(Qb + 32 + quad * 8);

        float m_run = NEG_INF;
        f32x4 acc[4] = {};   // acc[di][r] = O[query quad*4+r][d di*16+l]
        f32x4 acc_l = {};    // acc_l[r]  = rowsum l for query quad*4+r

        // ---- prefetch tile 0 (K to regs, V via DMA) ----
        bf16x8 kp0, kp1;
        int mv = 1;
        {
            const bf16* kg = Kbase + (size_t)kr * DMODEL + ks;
            kp0 = *(const bf16x8*)kg;
            kp1 = *(const bf16x8*)(kg + 8);
            gld_lds16((char*)Vs + vdst0, Vbase + voff0);
            gld_lds16((char*)Vs + vdst1, Vbase + voff1);
            if (wave == 0) mv = amask[b * S_LEN + lane];
        }
        __syncthreads();   // prior pass epilogue Os(=Ks[0]) reads complete
        {
            *(bf16x8*)&Ks[0][kr][ks]     = kp0;
            *(bf16x8*)&Ks[0][kr][ks + 8] = kp1;
            if (wave == 0) {
                mk[0][lane] = mv ? 0.0f : NEG_INF;
                unsigned long long bal = __ballot(mv != 0);
                if (lane == 0) flagv[0] = (bal == ~0ULL);
            }
        }
        __syncthreads();   // K store + V DMA (vmcnt drained at barrier) visible
        int buf = 0;

        for (int kt = 0; kt <= qt; ++kt) {
            const bool more = (kt < qt);
            if (more) {
                const bf16* kg = Kbase + (size_t)((kt + 1) * 64 + kr) * DMODEL + ks;
                kp0 = *(const bf16x8*)kg;
                kp1 = *(const bf16x8*)(kg + 8);
                const bf16* vt = Vbase + (size_t)(kt + 1) * 64 * DMODEL;
                const int nb = buf ^ 1;
                gld_lds16((char*)Vs + nb * 8192 + vdst0, vt + voff0);
                gld_lds16((char*)Vs + nb * 8192 + vdst1, vt + voff1);
                if (wave == 0) mv = amask[b * S_LEN + (kt + 1) * 64 + lane];
            }

            const int allv = flagv[buf];
            f32x4 sreg[4] = {};
            __builtin_amdgcn_s_setprio(1);
#pragma unroll
            for (int mi = 0; mi < 4; ++mi) {
                bf16x8 kf0 = *(const bf16x8*)&Ks[buf][mi * 16 + l][quad * 8];
                bf16x8 kf1 = *(const bf16x8*)&Ks[buf][mi * 16 + l][32 + quad * 8];
                sreg[mi] = __builtin_amdgcn_mfma_f32_16x16x32_bf16(kf0, qf0, sreg[mi], 0, 0, 0);
                sreg[mi] = __builtin_amdgcn_mfma_f32_16x16x32_bf16(kf1, qf1, sreg[mi], 0, 0, 0);
            }
            __builtin_amdgcn_s_setprio(0);

            // issue V tr-reads early: DS latency hides under softmax VALU
            frag4 va[16];
            const unsigned vtr = vtr0 + buf * 8192;
#define TRRD(i) asm volatile("ds_read_b64_tr_b16 %0, %1 offset:%2" \
                             : "=v"(va[i]) : "v"(vtr), "i"((i) * 512))
            TRRD(0);  TRRD(1);  TRRD(2);  TRRD(3);
            TRRD(4);  TRRD(5);  TRRD(6);  TRRD(7);
            TRRD(8);  TRRD(9);  TRRD(10); TRRD(11);
            TRRD(12); TRRD(13); TRRD(14); TRRD(15);
#undef TRRD

            if (!allv) {
#pragma unroll
                for (int mi = 0; mi < 4; ++mi) {
                    F4 m4; m4.v = *(const float4*)&mk[buf][mi * 16 + quad * 4];
#pragma unroll
                    for (int r = 0; r < 4; ++r) sreg[mi][r] += m4.f[r];
                }
            }
            if (kt == qt) {
#pragma unroll
                for (int mi = 0; mi < 4; ++mi)
#pragma unroll
                    for (int r = 0; r < 4; ++r)
                        if (mi * 16 + quad * 4 + r > wave * 16 + l)
                            sreg[mi][r] = NEG_INF;
            }

            // online softmax (per-query-l state); T13 defer-max gates rescale
            float mloc = sreg[0][0];
#pragma unroll
            for (int mi = 0; mi < 4; ++mi)
#pragma unroll
                for (int r = 0; r < 4; ++r) mloc = fmaxf(mloc, sreg[mi][r]);
            mloc = fmaxf(mloc, __shfl_xor(mloc, 16, 64));
            mloc = fmaxf(mloc, __shfl_xor(mloc, 32, 64));
            if (__any(mloc > m_run + 8.0f)) {
                const float mn = fmaxf(m_run, mloc);
                const float alpha = __builtin_amdgcn_exp2f(m_run - mn);
                m_run = mn;
                // acc rows are queries quad*4+r; fetch their alphas (lane id = query)
                const float a0 = __shfl(alpha, quad * 4 + 0, 64);
                const float a1 = __shfl(alpha, quad * 4 + 1, 64);
                const float a2 = __shfl(alpha, quad * 4 + 2, 64);
                const float a3 = __shfl(alpha, quad * 4 + 3, 64);
#pragma unroll
                for (int di = 0; di < 4; ++di) {
                    acc[di][0] *= a0; acc[di][1] *= a1;
                    acc[di][2] *= a2; acc[di][3] *= a3;
                }
                acc_l[0] *= a0; acc_l[1] *= a1; acc_l[2] *= a2; acc_l[3] *= a3;
            }
#pragma unroll
            for (int mi = 0; mi < 4; ++mi)
#pragma unroll
                for (int r = 0; r < 4; ++r)
                    sreg[mi][r] = __builtin_amdgcn_exp2f(sreg[mi][r] - m_run);

            // pack P -> A fragments (query=l rows, keys quad*4+j): direct layout
            frag4 pb[4];
#pragma unroll
            for (int mi = 0; mi < 4; ++mi) {
                union { bf16x4 h; frag4 s; } u;
                u.h[0] = (bf16)sreg[mi][0]; u.h[1] = (bf16)sreg[mi][1];
                u.h[2] = (bf16)sreg[mi][2]; u.h[3] = (bf16)sreg[mi][3];
                pb[mi] = u.s;
            }

            asm volatile("s_waitcnt lgkmcnt(0)" ::: "memory");
            __builtin_amdgcn_sched_barrier(0);
            __builtin_amdgcn_s_setprio(1);
#pragma unroll
            for (int mi = 0; mi < 4; ++mi) {
#pragma unroll
                for (int di = 0; di < 4; ++di)
                    acc[di] = mfma16(pb[mi], va[mi * 4 + di], acc[di]);
                acc_l = mfma16(pb[mi], onesf, acc_l);
            }
            __builtin_amdgcn_s_setprio(0);

            if (more) {
                const int nb = buf ^ 1;
                *(bf16x8*)&Ks[nb][kr][ks]     = kp0;
                *(bf16x8*)&Ks[nb][kr][ks + 8] = kp1;
                if (wave == 0) {
                    mk[nb][lane] = mv ? 0.0f : NEG_INF;
                    unsigned long long bal = __ballot(mv != 0);
                    if (lane == 0) flagv[nb] = (bal == ~0ULL);
                }
            }
            __syncthreads();
            buf ^= 1;
        }

        // epilogue: acc[di][r] = O[wave*16+quad*4+r][di*16+l]; 1/l in-lane.
        bf16 (*Os)[68] = (bf16 (*)[68])(&Ks[0][0][0]);   // Ks dead after loop
#pragma unroll
        for (int r = 0; r < 4; ++r) {
            const float rinv = 1.0f / acc_l[r];
#pragma unroll
            for (int di = 0; di < 4; ++di)
                Os[wave * 16 + quad * 4 + r][di * 16 + l] = (bf16)(acc[di][r] * rinv);
        }
        __syncthreads();
        {
            const int orow = tid >> 2, oseg = (tid & 3) * 16;
            bf16* Og = O + (size_t)(b * S_LEN + qt * 64 + orow) * DMODEL + h * HDIM + oseg;
            *(bf16x8*)Og       = *(const bf16x8*)&Os[orow][oseg];
            *(bf16x8*)(Og + 8) = *(const bf16x8*)&Os[orow][oseg + 8];
        }
    }
}

// ---------------- launcher ----------------
extern "C" void kernel_launch(void* const* d_in, const int* in_sizes, int n_in,
                              void* d_out, int out_size, void* d_ws, size_t ws_size,
                              hipStream_t stream) {
    const float* x     = (const float*)d_in[0];
    const int*   amask = (const int*)  d_in[1];
    const float* ln1_g = (const float*)d_in[2];
    const float* ln1_b = (const float*)d_in[3];
    const float* ln2_g = (const float*)d_in[4];
    const float* ln2_b = (const float*)d_in[5];
    const float* Wq = (const float*)d_in[6];  const float* bq = (const float*)d_in[7];
    const float* Wk = (const float*)d_in[8];  const float* bk = (const float*)d_in[9];
    const float* Wv = (const float*)d_in[10]; const float* bv = (const float*)d_in[11];
    const float* Wo = (const float*)d_in[12]; const float* bo = (const float*)d_in[13];
    const float* W1 = (const float*)d_in[14]; const float* b1 = (const float*)d_in[15];
    const float* W2 = (const float*)d_in[16]; const float* b2 = (const float*)d_in[17];
    float* out = (float*)d_out;

    char* ws = (char*)d_ws;
    const size_t WSML = (size_t)DMODEL * DMODEL * 2;
    const size_t WBIG = (size_t)DMODEL * DFF_ * 2;
    bf16* Wqt = (bf16*)(ws + 0 * WSML);
    bf16* Wkt = (bf16*)(ws + 1 * WSML);
    bf16* Wvt = (bf16*)(ws + 2 * WSML);
    bf16* Wot = (bf16*)(ws + 3 * WSML);
    bf16* W1t = (bf16*)(ws + 4 * WSML);
    bf16* W2t = (bf16*)(ws + 4 * WSML + WBIG);
    char* act = ws + 4 * WSML + 2 * WBIG;

    const size_t HB = (size_t)MROWS * DMODEL * 2;   // bf16 activation (12.6 MB)
    const size_t FB = (size_t)MROWS * DMODEL * 4;   // fp32 activation (25.2 MB)
    bf16*  h    = (bf16*)(act);            // LN1 out; later ctx; later h2
    bf16*  qb   = (bf16*)(act + HB);
    bf16*  kb   = (bf16*)(act + 2 * HB);
    bf16*  vb   = (bf16*)(act + 3 * HB);
    bf16*  ctx  = h;
    float* x1   = (float*)(act + 4 * HB);
    bf16*  f    = (bf16*)(act + 4 * HB + FB);      // FF1 out (50.3 MB)
    bf16*  h2   = h;
    bf16*  p0   = qb;                               // FF2 split-K partials
    bf16*  p1   = kb;
    float* zbias = (float*)vb;                      // zero bias; re-zeroed at LN2

    const float SCL = 0.125f * 1.44269504089f;  // 1/sqrt(64) * log2(e), folded into Q

    // 0. fused weight transpose+convert (one launch, 1728 tiles)
    wtrans_all_kernel<<<1728, 256, 0, stream>>>(Wq, Wk, Wv, Wo, W1, W2,
                                                Wqt, Wkt, Wvt, Wot, W1t, W2t);

    // 1. LN1 -> h (bf16)
    ln_kernel<bf16><<<MROWS, 256, 0, stream>>>(x, ln1_g, ln1_b, h, nullptr);
    // 2. QKV fused, bf16 out; Q pre-scaled by SCL  (1152 blocks)
    mgemm_kernel<128, false, false, true><<<dim3(DMODEL / 128, MROWS / 128, 3), 256, 0, stream>>>(
        h, Wqt, bq, qb, Wkt, bk, kb, Wvt, bv, vb, nullptr,
        MROWS, DMODEL, DMODEL, DMODEL, 0, 0, 0, SCL, 1.0f, 1.0f);
    // 3. flash attention -> ctx (bf16)  (768 paired-uniform blocks, 3/CU all-resident)
    mattn_kernel<<<dim3(32, NHEAD, 2), 256, 0, stream>>>(qb, kb, vb, amask, ctx);
    // 4. out proj + residual(x) -> x1 (fp32)  (MT=64: 768 blocks)
    mgemm_kernel<64, false, true, false><<<dim3(DMODEL / 128, MROWS / 64, 1), 256, 0, stream>>>(
        ctx, Wot, bo, x1, Wot, bo, x1, Wot, bo, x1, x,
        MROWS, DMODEL, DMODEL, DMODEL, 0, 0, 0, 1.0f, 1.0f, 1.0f);
    // 5. LN2 -> h2 (bf16) + zero zbias (vb dead now, before FF2 reads it)
    ln_kernel<bf16><<<MROWS, 256, 0, stream>>>(x1, ln2_g, ln2_b, h2, zbias);
    // 6. FF1 + relu -> f (bf16)  (1536 blocks)
    mgemm_kernel<128, true, false, true><<<dim3(DFF_ / 128, MROWS / 128, 1), 256, 0, stream>>>(
        h2, W1t, b1, f, W1t, b1, f, W1t, b1, f, nullptr,
        MROWS, DFF_, DMODEL, DMODEL, 0, 0, 0, 1.0f, 1.0f, 1.0f);
    // 7. FF2 split-K: z=0 -> K[0,1536) into p0; z=1 -> K[1536,3072) into p1
    mgemm_kernel<128, false, false, true><<<dim3(DMODEL / 128, MROWS / 128, 2), 256, 0, stream>>>(
        f, W2t, zbias, p0, W2t, zbias, p1, W2t, zbias, p1, nullptr,
        MROWS, DMODEL, DFF_, DFF_ / 2, 0, DFF_ / 2, 0, 1.0f, 1.0f, 1.0f);
    // 7b. combine: out = p0 + p1 + b2 + x1  (6144 blocks)
    ff2_combine_kernel<<<(MROWS * DMODEL) / 1024, 256, 0, stream>>>(p0, p1, b2, x1, out);
}

// Round 4
// 460.144 us; speedup vs baseline: 1.1269x; 1.0523x over previous
//
#include <hip/hip_runtime.h>
#include <hip/hip_bf16.h>
#include <math.h>

#define S_LEN 4096
#define DMODEL 768
#define NHEAD 12
#define HDIM 64
#define DFF_ 3072
#define MROWS 8192  // B*S

typedef __bf16 bf16;
typedef __bf16 bf16x4 __attribute__((ext_vector_type(4)));
typedef __bf16 bf16x8 __attribute__((ext_vector_type(8)));
typedef float f32x4 __attribute__((ext_vector_type(4)));
typedef short s16x4 __attribute__((ext_vector_type(4)));

union F4 { float4 v; float f[4]; };
union U2 { bf16 h[2]; unsigned u; };
union U8 { unsigned u[4]; bf16x8 v; };

// 16x16x16 bf16 MFMA: B-operand layout B[k=quad*4+j][n=l] == S^T C-layout,
// so softmax'd P feeds PV directly with ZERO cross-lane movement.
#if __has_builtin(__builtin_amdgcn_mfma_f32_16x16x16bf16_1k)
typedef s16x4 mf16_t;
#define MFMA16(a, b, c) __builtin_amdgcn_mfma_f32_16x16x16bf16_1k((a), (b), (c), 0, 0, 0)
#define HAVE_MFMA16 1
#elif __has_builtin(__builtin_amdgcn_mfma_f32_16x16x16_bf16)
typedef bf16x4 mf16_t;
#define MFMA16(a, b, c) __builtin_amdgcn_mfma_f32_16x16x16_bf16((a), (b), (c), 0, 0, 0)
#define HAVE_MFMA16 1
#else
#define HAVE_MFMA16 0
#endif

#if HAVE_MFMA16
union U4 { unsigned u[2]; mf16_t v; };
#endif

__device__ __forceinline__ void gld_lds16(void* lds, const void* g) {
    __builtin_amdgcn_global_load_lds(
        (const __attribute__((address_space(1))) unsigned int*)g,
        (__attribute__((address_space(3))) unsigned int*)lds, 16, 0, 0);
}

// ---------------- LayerNorm ----------------
template<typename OUT>
__global__ __launch_bounds__(256) void ln_kernel(const float* __restrict__ x,
                                                 const float* __restrict__ g,
                                                 const float* __restrict__ bta,
                                                 OUT* __restrict__ out,
                                                 float* __restrict__ zb) {
    const int row = blockIdx.x;
    const int t = threadIdx.x;
    if (zb && row == 0 && t < 192)
        ((float4*)zb)[t] = make_float4(0.f, 0.f, 0.f, 0.f);
    const float* xr = x + (size_t)row * DMODEL;
    float v0 = xr[t], v1 = xr[t + 256], v2 = xr[t + 512];
    float s = v0 + v1 + v2;
    float ss = v0 * v0 + v1 * v1 + v2 * v2;
    for (int o = 32; o > 0; o >>= 1) {
        s += __shfl_down(s, o, 64);
        ss += __shfl_down(ss, o, 64);
    }
    __shared__ float sm[4], sm2[4];
    const int w = t >> 6, lane = t & 63;
    if (lane == 0) { sm[w] = s; sm2[w] = ss; }
    __syncthreads();
    s = sm[0] + sm[1] + sm[2] + sm[3];
    ss = sm2[0] + sm2[1] + sm2[2] + sm2[3];
    const float mu = s * (1.0f / DMODEL);
    const float var = ss * (1.0f / DMODEL) - mu * mu;
    const float rs = rsqrtf(var + 1e-5f);
    OUT* orow = out + (size_t)row * DMODEL;
    orow[t]       = (OUT)((v0 - mu) * rs * g[t]       + bta[t]);
    orow[t + 256] = (OUT)((v1 - mu) * rs * g[t + 256] + bta[t + 256]);
    orow[t + 512] = (OUT)((v2 - mu) * rs * g[t + 512] + bta[t + 512]);
}

// ---------------- fused weight transpose+convert: all 6 weights, one launch ----------------
__global__ __launch_bounds__(256) void wtrans_all_kernel(
    const float* __restrict__ Wq, const float* __restrict__ Wk,
    const float* __restrict__ Wv, const float* __restrict__ Wo,
    const float* __restrict__ W1, const float* __restrict__ W2,
    bf16* __restrict__ Wqt, bf16* __restrict__ Wkt, bf16* __restrict__ Wvt,
    bf16* __restrict__ Wot, bf16* __restrict__ W1t, bf16* __restrict__ W2t) {
    int t = blockIdx.x;
    const float* W; bf16* Wt; int K, N;
    if      (t < 144)  { W = Wq; Wt = Wqt; K = 768;  N = 768;  }
    else if (t < 288)  { W = Wk; Wt = Wkt; K = 768;  N = 768;  t -= 144; }
    else if (t < 432)  { W = Wv; Wt = Wvt; K = 768;  N = 768;  t -= 288; }
    else if (t < 576)  { W = Wo; Wt = Wot; K = 768;  N = 768;  t -= 432; }
    else if (t < 1152) { W = W1; Wt = W1t; K = 768;  N = 3072; t -= 576; }
    else               { W = W2; Wt = W2t; K = 3072; N = 768;  t -= 1152; }
    const int nx = N >> 6;
    const int n0 = (t % nx) * 64, k0 = (t / nx) * 64;

    __shared__ float tile[64][65];
    const int tid = threadIdx.x;
    const int lr = tid >> 4, lc = (tid & 15) << 2;
#pragma unroll
    for (int i = 0; i < 4; ++i) {
        const int r = lr + i * 16;
        F4 w; w.v = *(const float4*)&W[(size_t)(k0 + r) * N + n0 + lc];
#pragma unroll
        for (int j = 0; j < 4; ++j) tile[r][lc + j] = w.f[j];
    }
    __syncthreads();
#pragma unroll
    for (int i = 0; i < 4; ++i) {
        const int n = lr + i * 16;
        bf16x4 o;
#pragma unroll
        for (int j = 0; j < 4; ++j) o[j] = (bf16)tile[lc + j][n];
        *(bf16x4*)&Wt[(size_t)(n0 + n) * K + k0 + lc] = o;
    }
}

// ---------------- bf16 MFMA GEMM, MT x 128 tile, BK=64, XCD-swizzled ----------------
template<int MT, bool RELU, bool RES, bool OUT_BF16>
__global__ __launch_bounds__(256) void mgemm_kernel(
    const bf16* __restrict__ A,
    const bf16* __restrict__ Wt0, const float* __restrict__ bias0, void* __restrict__ C0,
    const bf16* __restrict__ Wt1, const float* __restrict__ bias1, void* __restrict__ C1,
    const bf16* __restrict__ Wt2, const float* __restrict__ bias2, void* __restrict__ C2,
    const float* __restrict__ R, int M, int N, int K, int Kloop,
    int koff0, int koff1, int koff2,
    float sc0, float sc1, float sc2) {
    const bf16* Wt = Wt0; const float* bias = bias0; void* C = C0; float sc = sc0; int koff = koff0;
    if (blockIdx.z == 1) { Wt = Wt1; bias = bias1; C = C1; sc = sc1; koff = koff1; }
    if (blockIdx.z == 2) { Wt = Wt2; bias = bias2; C = C2; sc = sc2; koff = koff2; }

    // T1: XCD-aware bijective tile remap. Every launch has (gx*gy) % 8 == 0 and
    // per-z slices stay 8-aligned, so dispatch index i (-> XCD i%8) walks a
    // contiguous lid chunk per XCD: neighboring tiles share A/B panels in L2.
    const int gx = gridDim.x;
    const int nwg = gx * gridDim.y;
    const int chunk = nwg >> 3;
    int lid = blockIdx.y * gx + blockIdx.x;
    lid = (lid & 7) * chunk + (lid >> 3);
    const int row0 = (lid / gx) * MT, col0 = (lid % gx) * 128;

    constexpr int NI = (MT == 128) ? 4 : 2;
    __shared__ bf16 As[2][MT * 32];
    __shared__ bf16 Bs[2][128 * 32];

    const int tid = threadIdx.x;
    const int wave = tid >> 6, lane = tid & 63;
    const int wr = (MT == 128) ? (wave >> 1) * 64 : 0;
    const int wc = (MT == 128) ? (wave & 1) * 64 : wave * 32;
    const int mrow = lane & 15, kq = (lane >> 4) * 8;

    const int st_row = (lane >> 2);
    const int st_off = (lane & 3) * 16;

    f32x4 acc[4][NI] = {};

    const char* Ab = (const char*)(A + (size_t)row0 * K + koff);
    const char* Bb = (const char*)(Wt + (size_t)col0 * K + koff);
    const size_t strideA = (size_t)K * 2;

    for (int k0 = 0; k0 < Kloop; k0 += 64) {
#pragma unroll
        for (int s = 0; s < 2; ++s) {
            const int kk = k0 + s * 32;
            if (MT == 128) {
#pragma unroll
                for (int issue = 0; issue < 2; ++issue) {
                    const int r = wave * 32 + issue * 16 + st_row;
                    gld_lds16((char*)As[s] + (wave * 32 + issue * 16) * 64,
                              Ab + (size_t)r * strideA + kk * 2 + st_off);
                }
            } else {
                const int r = wave * 16 + st_row;
                gld_lds16((char*)As[s] + (wave * 16) * 64,
                          Ab + (size_t)r * strideA + kk * 2 + st_off);
            }
#pragma unroll
            for (int issue = 0; issue < 2; ++issue) {
                const int r = wave * 32 + issue * 16 + st_row;
                gld_lds16((char*)Bs[s] + (wave * 32 + issue * 16) * 64,
                          Bb + (size_t)r * strideA + kk * 2 + st_off);
            }
        }
        __syncthreads();
#pragma unroll
        for (int s = 0; s < 2; ++s) {
            bf16x8 af[4], bfr[NI];
#pragma unroll
            for (int mi = 0; mi < 4; ++mi)
                af[mi] = *(const bf16x8*)&As[s][(wr + mi * 16 + mrow) * 32 + kq];
#pragma unroll
            for (int ni = 0; ni < NI; ++ni)
                bfr[ni] = *(const bf16x8*)&Bs[s][(wc + ni * 16 + mrow) * 32 + kq];
#pragma unroll
            for (int mi = 0; mi < 4; ++mi)
#pragma unroll
                for (int ni = 0; ni < NI; ++ni)
                    acc[mi][ni] = __builtin_amdgcn_mfma_f32_16x16x32_bf16(
                        af[mi], bfr[ni], acc[mi][ni], 0, 0, 0);
        }
        __syncthreads();
    }

    const int quad = lane >> 4;
    float bv[NI];
#pragma unroll
    for (int ni = 0; ni < NI; ++ni) bv[ni] = bias[col0 + wc + ni * 16 + mrow];
#pragma unroll
    for (int mi = 0; mi < 4; ++mi) {
#pragma unroll
        for (int r = 0; r < 4; ++r) {
            const int row = row0 + wr + mi * 16 + quad * 4 + r;
#pragma unroll
            for (int ni = 0; ni < NI; ++ni) {
                const int col = col0 + wc + ni * 16 + mrow;
                float v = acc[mi][ni][r] + bv[ni];
                if (RES) v += R[(size_t)row * N + col];
                v *= sc;
                if (RELU) v = fmaxf(v, 0.0f);
                if (OUT_BF16) ((bf16*)C)[(size_t)row * N + col] = (bf16)v;
                else          ((float*)C)[(size_t)row * N + col] = v;
            }
        }
    }
}

// ---------------- Transposed-S MFMA flash attention (shfl-free PV + MFMA-fused l) ----------------
// S^T = K·Q^T. PV uses 16x16x16 MFMA (B-layout == S^T C-layout: no shfl).
// Row-sum l fused into PV via a ones-row appended to V^T (row 64): only D-row 0
// reads the ones row, so garbage in rows 65..79 never contaminates acc_l[0];
// alpha rescale keeps acc_l consistent (first-iter alpha=0 clears init state).
// grid (32,H,B) = 768 paired-uniform blocks; double-buffered K/V, 1 barrier/iter.
// (r0 structure, byte-identical: r1/r3 restructures both measured slower.)
__global__ __launch_bounds__(256) void mattn_kernel(
    const bf16* __restrict__ Q, const bf16* __restrict__ K,
    const bf16* __restrict__ V, const int* __restrict__ amask,
    bf16* __restrict__ O) {
    const int bx = blockIdx.x, h = blockIdx.y, b = blockIdx.z;

    __shared__ bf16 Ks[2][64][68];   // [buf][key][d]  (136 B rows: conflict-free)
#if HAVE_MFMA16
    __shared__ bf16 Vt[2][80][68];   // [buf][d][key]; row 64 = ones (l fusion)
#else
    __shared__ bf16 Vt[2][64][68];
#endif
    __shared__ bf16 Os[64][68];      // epilogue bounce
    __shared__ float mk[2][64];
    __shared__ int flagv[2];

    const int tid = threadIdx.x;
    const int wave = tid >> 6, lane = tid & 63;
    const int l = lane & 15, quad = lane >> 4;
#if !HAVE_MFMA16
    const int qh = quad >> 1;
    const int srcA = (quad & 1) * 32 + l;
    const int srcB = srcA + 16;
#endif
    const float NEG_INF = -__builtin_huge_valf();

    const int kr = tid >> 2, ks = (tid & 3) * 16;          // K tile staging
    const int vk0 = (tid & 31) * 2, vds = (tid >> 5) * 8;  // V transpose staging

    const bf16* Kbase = K + (size_t)b * S_LEN * DMODEL + h * HDIM;
    const bf16* Vbase = V + (size_t)b * S_LEN * DMODEL + h * HDIM;

#if HAVE_MFMA16
    // ones row for l-fusion (row 64 of both V^T buffers); staging never touches
    // rows >= 64, so this survives the whole kernel. Visible after first barrier.
    if (tid < 68) {
        Vt[0][64][tid] = (bf16)1.0f;
        Vt[1][64][tid] = (bf16)1.0f;
    }
#endif

#pragma unroll 1
    for (int pass = 0; pass < 2; ++pass) {
        const int qt = pass ? bx : (63 - bx);

        const bf16* Qb = Q + (size_t)(b * S_LEN + qt * 64 + wave * 16 + l) * DMODEL + h * HDIM;
        const bf16x8 qf0 = *(const bf16x8*)(Qb + quad * 8);
        const bf16x8 qf1 = *(const bf16x8*)(Qb + 32 + quad * 8);

        float m_run = NEG_INF;
#if !HAVE_MFMA16
        float l_run = 0.0f;
#endif
        f32x4 acc[4] = {};
#if HAVE_MFMA16
        f32x4 acc_l = {};   // D-row 0 (quad-0 lanes, elem 0) accumulates l
#endif

        // ---- prefetch tile 0 into registers ----
        bf16x8 kp0, kp1, vp0, vp1;
        int mv = 1;
        {
            const bf16* kg = Kbase + (size_t)kr * DMODEL + ks;
            kp0 = *(const bf16x8*)kg;
            kp1 = *(const bf16x8*)(kg + 8);
            const bf16* vg = Vbase + (size_t)vk0 * DMODEL + vds;
            vp0 = *(const bf16x8*)vg;
            vp1 = *(const bf16x8*)(vg + DMODEL);
            if (wave == 0) mv = amask[b * S_LEN + lane];
        }
        __syncthreads();   // prior pass epilogue LDS reads complete
        {
            *(bf16x8*)&Ks[0][kr][ks]     = kp0;
            *(bf16x8*)&Ks[0][kr][ks + 8] = kp1;
#pragma unroll
            for (int i = 0; i < 8; ++i) {
                U2 w; w.h[0] = vp0[i]; w.h[1] = vp1[i];
                *(unsigned*)&Vt[0][vds + i][vk0] = w.u;
            }
            if (wave == 0) {
                mk[0][lane] = mv ? 0.0f : NEG_INF;
                unsigned long long bal = __ballot(mv != 0);
                if (lane == 0) flagv[0] = (bal == ~0ULL);
            }
        }
        __syncthreads();
        int buf = 0;

        for (int kt = 0; kt <= qt; ++kt) {
            const bool more = (kt < qt);
            if (more) {
                const bf16* kg = Kbase + (size_t)((kt + 1) * 64 + kr) * DMODEL + ks;
                kp0 = *(const bf16x8*)kg;
                kp1 = *(const bf16x8*)(kg + 8);
                const bf16* vg = Vbase + (size_t)((kt + 1) * 64 + vk0) * DMODEL + vds;
                vp0 = *(const bf16x8*)vg;
                vp1 = *(const bf16x8*)(vg + DMODEL);
                if (wave == 0) mv = amask[b * S_LEN + (kt + 1) * 64 + lane];
            }

            const int allv = flagv[buf];
            f32x4 sreg[4] = {};
#pragma unroll
            for (int mi = 0; mi < 4; ++mi) {
                bf16x8 kf0 = *(const bf16x8*)&Ks[buf][mi * 16 + l][quad * 8];
                bf16x8 kf1 = *(const bf16x8*)&Ks[buf][mi * 16 + l][32 + quad * 8];
                sreg[mi] = __builtin_amdgcn_mfma_f32_16x16x32_bf16(kf0, qf0, sreg[mi], 0, 0, 0);
                sreg[mi] = __builtin_amdgcn_mfma_f32_16x16x32_bf16(kf1, qf1, sreg[mi], 0, 0, 0);
            }
            if (!allv) {
#pragma unroll
                for (int mi = 0; mi < 4; ++mi) {
                    F4 m4; m4.v = *(const float4*)&mk[buf][mi * 16 + quad * 4];
#pragma unroll
                    for (int r = 0; r < 4; ++r) sreg[mi][r] += m4.f[r];
                }
            }
            if (kt == qt) {
#pragma unroll
                for (int mi = 0; mi < 4; ++mi)
#pragma unroll
                    for (int r = 0; r < 4; ++r)
                        if (mi * 16 + quad * 4 + r > wave * 16 + l)
                            sreg[mi][r] = NEG_INF;
            }

            // online softmax: max-reduce (15 max + 2 shfl), exp2, alpha rescale.
            float mloc = sreg[0][0];
#pragma unroll
            for (int mi = 0; mi < 4; ++mi)
#pragma unroll
                for (int r = 0; r < 4; ++r) mloc = fmaxf(mloc, sreg[mi][r]);
            mloc = fmaxf(mloc, __shfl_xor(mloc, 16, 64));
            mloc = fmaxf(mloc, __shfl_xor(mloc, 32, 64));
            const float mn = fmaxf(m_run, mloc);
            const float alpha = __builtin_amdgcn_exp2f(m_run - mn);
            m_run = mn;
#pragma unroll
            for (int mi = 0; mi < 4; ++mi)
#pragma unroll
                for (int r = 0; r < 4; ++r)
                    sreg[mi][r] = __builtin_amdgcn_exp2f(sreg[mi][r] - mn);
#if !HAVE_MFMA16
            float ls = 0.0f;
#pragma unroll
            for (int mi = 0; mi < 4; ++mi)
#pragma unroll
                for (int r = 0; r < 4; ++r) ls += sreg[mi][r];
            ls += __shfl_xor(ls, 16, 64);
            ls += __shfl_xor(ls, 32, 64);
            l_run = l_run * alpha + ls;
#endif
#pragma unroll
            for (int mi = 0; mi < 4; ++mi)
#pragma unroll
                for (int r = 0; r < 4; ++r) acc[mi][r] *= alpha;
#if HAVE_MFMA16
#pragma unroll
            for (int r = 0; r < 4; ++r) acc_l[r] *= alpha;
#endif

            // pack P^T to bf16 dwords (keys mi*16+quad*4+{0..3}, query l)
            unsigned pk[4][2];
#pragma unroll
            for (int mi = 0; mi < 4; ++mi) {
                U2 w0; w0.h[0] = (bf16)sreg[mi][0]; w0.h[1] = (bf16)sreg[mi][1];
                U2 w1; w1.h[0] = (bf16)sreg[mi][2]; w1.h[1] = (bf16)sreg[mi][3];
                pk[mi][0] = w0.u; pk[mi][1] = w1.u;
            }

#if HAVE_MFMA16
            // O^T += V^T · P^T ; extra MFMA on ones-row accumulates l into acc_l.
#pragma unroll
            for (int mi = 0; mi < 4; ++mi) {
                U4 pb; pb.u[0] = pk[mi][0]; pb.u[1] = pk[mi][1];
#pragma unroll
                for (int di = 0; di < 4; ++di) {
                    mf16_t va = *(const mf16_t*)&Vt[buf][di * 16 + l][mi * 16 + quad * 4];
                    acc[di] = MFMA16(va, pb.v, acc[di]);
                }
                mf16_t vl = *(const mf16_t*)&Vt[buf][64 + l][mi * 16 + quad * 4];
                acc_l = MFMA16(vl, pb.v, acc_l);
            }
#else
            bf16x8 pfrag[2];
#pragma unroll
            for (int kc = 0; kc < 2; ++kc) {
                U8 u;
#pragma unroll
                for (int t = 0; t < 2; ++t) {
                    const unsigned a0 = (unsigned)__shfl((int)pk[2 * kc][t],     srcA, 64);
                    const unsigned b0 = (unsigned)__shfl((int)pk[2 * kc + 1][t], srcA, 64);
                    u.u[t] = qh ? b0 : a0;
                    const unsigned a1 = (unsigned)__shfl((int)pk[2 * kc][t],     srcB, 64);
                    const unsigned b1 = (unsigned)__shfl((int)pk[2 * kc + 1][t], srcB, 64);
                    u.u[2 + t] = qh ? b1 : a1;
                }
                pfrag[kc] = u.v;
            }
#pragma unroll
            for (int mi = 0; mi < 4; ++mi) {
                bf16x8 vf0 = *(const bf16x8*)&Vt[buf][mi * 16 + l][quad * 8];
                bf16x8 vf1 = *(const bf16x8*)&Vt[buf][mi * 16 + l][32 + quad * 8];
                acc[mi] = __builtin_amdgcn_mfma_f32_16x16x32_bf16(vf0, pfrag[0], acc[mi], 0, 0, 0);
                acc[mi] = __builtin_amdgcn_mfma_f32_16x16x32_bf16(vf1, pfrag[1], acc[mi], 0, 0, 0);
            }
#endif

            if (more) {
                const int nb = buf ^ 1;
                *(bf16x8*)&Ks[nb][kr][ks]     = kp0;
                *(bf16x8*)&Ks[nb][kr][ks + 8] = kp1;
#pragma unroll
                for (int i = 0; i < 8; ++i) {
                    U2 w; w.h[0] = vp0[i]; w.h[1] = vp1[i];
                    *(unsigned*)&Vt[nb][vds + i][vk0] = w.u;
                }
                if (wave == 0) {
                    mk[nb][lane] = mv ? 0.0f : NEG_INF;
                    unsigned long long bal = __ballot(mv != 0);
                    if (lane == 0) flagv[nb] = (bal == ~0ULL);
                }
            }
            __syncthreads();
            buf ^= 1;
        }

#if HAVE_MFMA16
        // l lives in acc_l[0] of quad-0 lane with col==query; broadcast via shfl.
        const float l_run = __shfl(acc_l[0], l, 64);
#endif
        const float rinv = 1.0f / l_run;
#pragma unroll
        for (int mi = 0; mi < 4; ++mi) {
            U2 w0; w0.h[0] = (bf16)(acc[mi][0] * rinv); w0.h[1] = (bf16)(acc[mi][1] * rinv);
            U2 w1; w1.h[0] = (bf16)(acc[mi][2] * rinv); w1.h[1] = (bf16)(acc[mi][3] * rinv);
            *(unsigned*)&Os[wave * 16 + l][mi * 16 + quad * 4]     = w0.u;
            *(unsigned*)&Os[wave * 16 + l][mi * 16 + quad * 4 + 2] = w1.u;
        }
        __syncthreads();
        {
            const int orow = tid >> 2, oseg = (tid & 3) * 16;
            bf16* Og = O + (size_t)(b * S_LEN + qt * 64 + orow) * DMODEL + h * HDIM + oseg;
            *(bf16x8*)Og       = *(const bf16x8*)&Os[orow][oseg];
            *(bf16x8*)(Og + 8) = *(const bf16x8*)&Os[orow][oseg + 8];
        }
    }
}

// ---------------- launcher ----------------
extern "C" void kernel_launch(void* const* d_in, const int* in_sizes, int n_in,
                              void* d_out, int out_size, void* d_ws, size_t ws_size,
                              hipStream_t stream) {
    const float* x     = (const float*)d_in[0];
    const int*   amask = (const int*)  d_in[1];
    const float* ln1_g = (const float*)d_in[2];
    const float* ln1_b = (const float*)d_in[3];
    const float* ln2_g = (const float*)d_in[4];
    const float* ln2_b = (const float*)d_in[5];
    const float* Wq = (const float*)d_in[6];  const float* bq = (const float*)d_in[7];
    const float* Wk = (const float*)d_in[8];  const float* bk = (const float*)d_in[9];
    const float* Wv = (const float*)d_in[10]; const float* bv = (const float*)d_in[11];
    const float* Wo = (const float*)d_in[12]; const float* bo = (const float*)d_in[13];
    const float* W1 = (const float*)d_in[14]; const float* b1 = (const float*)d_in[15];
    const float* W2 = (const float*)d_in[16]; const float* b2 = (const float*)d_in[17];
    float* out = (float*)d_out;

    char* ws = (char*)d_ws;
    const size_t WSML = (size_t)DMODEL * DMODEL * 2;
    const size_t WBIG = (size_t)DMODEL * DFF_ * 2;
    bf16* Wqt = (bf16*)(ws + 0 * WSML);
    bf16* Wkt = (bf16*)(ws + 1 * WSML);
    bf16* Wvt = (bf16*)(ws + 2 * WSML);
    bf16* Wot = (bf16*)(ws + 3 * WSML);
    bf16* W1t = (bf16*)(ws + 4 * WSML);
    bf16* W2t = (bf16*)(ws + 4 * WSML + WBIG);
    char* act = ws + 4 * WSML + 2 * WBIG;

    const size_t HB = (size_t)MROWS * DMODEL * 2;   // bf16 activation (12.6 MB)
    const size_t FB = (size_t)MROWS * DMODEL * 4;   // fp32 activation (25.2 MB)
    bf16*  h    = (bf16*)(act);            // LN1 out; later ctx; later h2
    bf16*  qb   = (bf16*)(act + HB);
    bf16*  kb   = (bf16*)(act + 2 * HB);
    bf16*  vb   = (bf16*)(act + 3 * HB);
    bf16*  ctx  = h;
    float* x1   = (float*)(act + 4 * HB);
    bf16*  f    = (bf16*)(act + 4 * HB + FB);      // FF1 out (50.3 MB)
    bf16*  h2   = h;

    const float SCL = 0.125f * 1.44269504089f;  // 1/sqrt(64) * log2(e), folded into Q

    // 0. fused weight transpose+convert (one launch, 1728 tiles)
    wtrans_all_kernel<<<1728, 256, 0, stream>>>(Wq, Wk, Wv, Wo, W1, W2,
                                                Wqt, Wkt, Wvt, Wot, W1t, W2t);

    // 1. LN1 -> h (bf16)
    ln_kernel<bf16><<<MROWS, 256, 0, stream>>>(x, ln1_g, ln1_b, h, nullptr);
    // 2. QKV fused, bf16 out; Q pre-scaled by SCL  (1152 blocks)
    mgemm_kernel<128, false, false, true><<<dim3(DMODEL / 128, MROWS / 128, 3), 256, 0, stream>>>(
        h, Wqt, bq, qb, Wkt, bk, kb, Wvt, bv, vb, nullptr,
        MROWS, DMODEL, DMODEL, DMODEL, 0, 0, 0, SCL, 1.0f, 1.0f);
    // 3. flash attention -> ctx (bf16)  (768 paired-uniform blocks)
    mattn_kernel<<<dim3(32, NHEAD, 2), 256, 0, stream>>>(qb, kb, vb, amask, ctx);
    // 4. out proj + residual(x) -> x1 (fp32)  (MT=64: 768 blocks)
    mgemm_kernel<64, false, true, false><<<dim3(DMODEL / 128, MROWS / 64, 1), 256, 0, stream>>>(
        ctx, Wot, bo, x1, Wot, bo, x1, Wot, bo, x1, x,
        MROWS, DMODEL, DMODEL, DMODEL, 0, 0, 0, 1.0f, 1.0f, 1.0f);
    // 5. LN2 -> h2 (bf16)
    ln_kernel<bf16><<<MROWS, 256, 0, stream>>>(x1, ln2_g, ln2_b, h2, nullptr);
    // 6. FF1 + relu -> f (bf16)  (1536 blocks)
    mgemm_kernel<128, true, false, true><<<dim3(DFF_ / 128, MROWS / 128, 1), 256, 0, stream>>>(
        h2, W1t, b1, f, W1t, b1, f, W1t, b1, f, nullptr,
        MROWS, DFF_, DMODEL, DMODEL, 0, 0, 0, 1.0f, 1.0f, 1.0f);
    // 7. FF2 full-K, MT=64 (768 blocks): out = f@W2 + b2 + x1, fp32 direct.
    //    Replaces split-K + combine: no partial round-trip, one fewer launch.
    mgemm_kernel<64, false, true, false><<<dim3(DMODEL / 128, MROWS / 64, 1), 256, 0, stream>>>(
        f, W2t, b2, out, W2t, b2, out, W2t, b2, out, x1,
        MROWS, DMODEL, DFF_, DFF_, 0, 0, 0, 1.0f, 1.0f, 1.0f);
}

// Round 5
// 450.304 us; speedup vs baseline: 1.1515x; 1.0219x over previous
//
#include <hip/hip_runtime.h>
#include <hip/hip_bf16.h>
#include <math.h>

#define S_LEN 4096
#define DMODEL 768
#define NHEAD 12
#define HDIM 64
#define DFF_ 3072
#define MROWS 8192  // B*S

typedef __bf16 bf16;
typedef __bf16 bf16x4 __attribute__((ext_vector_type(4)));
typedef __bf16 bf16x8 __attribute__((ext_vector_type(8)));
typedef float f32x4 __attribute__((ext_vector_type(4)));
typedef short s16x4 __attribute__((ext_vector_type(4)));

union F4 { float4 v; float f[4]; };
union U2 { bf16 h[2]; unsigned u; };
union U8 { unsigned u[4]; bf16x8 v; };

// 16x16x16 bf16 MFMA: B-operand layout B[k=quad*4+j][n=l] == S^T C-layout,
// so softmax'd P feeds PV directly with ZERO cross-lane movement.
#if __has_builtin(__builtin_amdgcn_mfma_f32_16x16x16bf16_1k)
typedef s16x4 mf16_t;
#define MFMA16(a, b, c) __builtin_amdgcn_mfma_f32_16x16x16bf16_1k((a), (b), (c), 0, 0, 0)
#define HAVE_MFMA16 1
#elif __has_builtin(__builtin_amdgcn_mfma_f32_16x16x16_bf16)
typedef bf16x4 mf16_t;
#define MFMA16(a, b, c) __builtin_amdgcn_mfma_f32_16x16x16_bf16((a), (b), (c), 0, 0, 0)
#define HAVE_MFMA16 1
#else
#define HAVE_MFMA16 0
#endif

#if HAVE_MFMA16
union U4 { unsigned u[2]; mf16_t v; };
#endif

__device__ __forceinline__ void gld_lds16(void* lds, const void* g) {
    __builtin_amdgcn_global_load_lds(
        (const __attribute__((address_space(1))) unsigned int*)g,
        (__attribute__((address_space(3))) unsigned int*)lds, 16, 0, 0);
}

// ---------------- LayerNorm ----------------
template<typename OUT>
__global__ __launch_bounds__(256) void ln_kernel(const float* __restrict__ x,
                                                 const float* __restrict__ g,
                                                 const float* __restrict__ bta,
                                                 OUT* __restrict__ out,
                                                 float* __restrict__ zb) {
    const int row = blockIdx.x;
    const int t = threadIdx.x;
    if (zb && row == 0 && t < 192)
        ((float4*)zb)[t] = make_float4(0.f, 0.f, 0.f, 0.f);
    const float* xr = x + (size_t)row * DMODEL;
    float v0 = xr[t], v1 = xr[t + 256], v2 = xr[t + 512];
    float s = v0 + v1 + v2;
    float ss = v0 * v0 + v1 * v1 + v2 * v2;
    for (int o = 32; o > 0; o >>= 1) {
        s += __shfl_down(s, o, 64);
        ss += __shfl_down(ss, o, 64);
    }
    __shared__ float sm[4], sm2[4];
    const int w = t >> 6, lane = t & 63;
    if (lane == 0) { sm[w] = s; sm2[w] = ss; }
    __syncthreads();
    s = sm[0] + sm[1] + sm[2] + sm[3];
    ss = sm2[0] + sm2[1] + sm2[2] + sm2[3];
    const float mu = s * (1.0f / DMODEL);
    const float var = ss * (1.0f / DMODEL) - mu * mu;
    const float rs = rsqrtf(var + 1e-5f);
    OUT* orow = out + (size_t)row * DMODEL;
    orow[t]       = (OUT)((v0 - mu) * rs * g[t]       + bta[t]);
    orow[t + 256] = (OUT)((v1 - mu) * rs * g[t + 256] + bta[t + 256]);
    orow[t + 512] = (OUT)((v2 - mu) * rs * g[t + 512] + bta[t + 512]);
}

// ---------------- fused weight transpose+convert: all 6 weights, one launch ----------------
__global__ __launch_bounds__(256) void wtrans_all_kernel(
    const float* __restrict__ Wq, const float* __restrict__ Wk,
    const float* __restrict__ Wv, const float* __restrict__ Wo,
    const float* __restrict__ W1, const float* __restrict__ W2,
    bf16* __restrict__ Wqt, bf16* __restrict__ Wkt, bf16* __restrict__ Wvt,
    bf16* __restrict__ Wot, bf16* __restrict__ W1t, bf16* __restrict__ W2t) {
    int t = blockIdx.x;
    const float* W; bf16* Wt; int K, N;
    if      (t < 144)  { W = Wq; Wt = Wqt; K = 768;  N = 768;  }
    else if (t < 288)  { W = Wk; Wt = Wkt; K = 768;  N = 768;  t -= 144; }
    else if (t < 432)  { W = Wv; Wt = Wvt; K = 768;  N = 768;  t -= 288; }
    else if (t < 576)  { W = Wo; Wt = Wot; K = 768;  N = 768;  t -= 432; }
    else if (t < 1152) { W = W1; Wt = W1t; K = 768;  N = 3072; t -= 576; }
    else               { W = W2; Wt = W2t; K = 3072; N = 768;  t -= 1152; }
    const int nx = N >> 6;
    const int n0 = (t % nx) * 64, k0 = (t / nx) * 64;

    __shared__ float tile[64][65];
    const int tid = threadIdx.x;
    const int lr = tid >> 4, lc = (tid & 15) << 2;
#pragma unroll
    for (int i = 0; i < 4; ++i) {
        const int r = lr + i * 16;
        F4 w; w.v = *(const float4*)&W[(size_t)(k0 + r) * N + n0 + lc];
#pragma unroll
        for (int j = 0; j < 4; ++j) tile[r][lc + j] = w.f[j];
    }
    __syncthreads();
#pragma unroll
    for (int i = 0; i < 4; ++i) {
        const int n = lr + i * 16;
        bf16x4 o;
#pragma unroll
        for (int j = 0; j < 4; ++j) o[j] = (bf16)tile[lc + j][n];
        *(bf16x4*)&Wt[(size_t)(n0 + n) * K + k0 + lc] = o;
    }
}

// ---------------- bf16 MFMA GEMM, MT x 128 tile, BK=64, XCD-swizzled ----------------
// MFMA operands SWAPPED (mfma(b,a,acc) -> C^T fragment layout): each lane's 4
// acc elements are 4 CONSECUTIVE output columns (row=mrow, col=quad*4+r), so
// the epilogue is float4 bias / float4 residual / bf16x4|float4 vector stores
// (16 vector stores/thread vs 64 scalar) at zero inner-loop cost.
template<int MT, bool RELU, bool RES, bool OUT_BF16>
__global__ __launch_bounds__(256) void mgemm_kernel(
    const bf16* __restrict__ A,
    const bf16* __restrict__ Wt0, const float* __restrict__ bias0, void* __restrict__ C0,
    const bf16* __restrict__ Wt1, const float* __restrict__ bias1, void* __restrict__ C1,
    const bf16* __restrict__ Wt2, const float* __restrict__ bias2, void* __restrict__ C2,
    const float* __restrict__ R, int M, int N, int K, int Kloop,
    int koff0, int koff1, int koff2,
    float sc0, float sc1, float sc2) {
    const bf16* Wt = Wt0; const float* bias = bias0; void* C = C0; float sc = sc0; int koff = koff0;
    if (blockIdx.z == 1) { Wt = Wt1; bias = bias1; C = C1; sc = sc1; koff = koff1; }
    if (blockIdx.z == 2) { Wt = Wt2; bias = bias2; C = C2; sc = sc2; koff = koff2; }

    // T1: XCD-aware bijective tile remap ((gx*gy) % 8 == 0 for all launches).
    const int gx = gridDim.x;
    const int nwg = gx * gridDim.y;
    const int chunk = nwg >> 3;
    int lid = blockIdx.y * gx + blockIdx.x;
    lid = (lid & 7) * chunk + (lid >> 3);
    const int row0 = (lid / gx) * MT, col0 = (lid % gx) * 128;

    constexpr int NI = (MT == 128) ? 4 : 2;
    __shared__ bf16 As[2][MT * 32];
    __shared__ bf16 Bs[2][128 * 32];

    const int tid = threadIdx.x;
    const int wave = tid >> 6, lane = tid & 63;
    const int wr = (MT == 128) ? (wave >> 1) * 64 : 0;
    const int wc = (MT == 128) ? (wave & 1) * 64 : wave * 32;
    const int mrow = lane & 15, kq = (lane >> 4) * 8;

    const int st_row = (lane >> 2);
    const int st_off = (lane & 3) * 16;

    f32x4 acc[4][NI] = {};

    const char* Ab = (const char*)(A + (size_t)row0 * K + koff);
    const char* Bb = (const char*)(Wt + (size_t)col0 * K + koff);
    const size_t strideA = (size_t)K * 2;

    for (int k0 = 0; k0 < Kloop; k0 += 64) {
#pragma unroll
        for (int s = 0; s < 2; ++s) {
            const int kk = k0 + s * 32;
            if (MT == 128) {
#pragma unroll
                for (int issue = 0; issue < 2; ++issue) {
                    const int r = wave * 32 + issue * 16 + st_row;
                    gld_lds16((char*)As[s] + (wave * 32 + issue * 16) * 64,
                              Ab + (size_t)r * strideA + kk * 2 + st_off);
                }
            } else {
                const int r = wave * 16 + st_row;
                gld_lds16((char*)As[s] + (wave * 16) * 64,
                          Ab + (size_t)r * strideA + kk * 2 + st_off);
            }
#pragma unroll
            for (int issue = 0; issue < 2; ++issue) {
                const int r = wave * 32 + issue * 16 + st_row;
                gld_lds16((char*)Bs[s] + (wave * 32 + issue * 16) * 64,
                          Bb + (size_t)r * strideA + kk * 2 + st_off);
            }
        }
        __syncthreads();
#pragma unroll
        for (int s = 0; s < 2; ++s) {
            bf16x8 af[4], bfr[NI];
#pragma unroll
            for (int mi = 0; mi < 4; ++mi)
                af[mi] = *(const bf16x8*)&As[s][(wr + mi * 16 + mrow) * 32 + kq];
#pragma unroll
            for (int ni = 0; ni < NI; ++ni)
                bfr[ni] = *(const bf16x8*)&Bs[s][(wc + ni * 16 + mrow) * 32 + kq];
#pragma unroll
            for (int mi = 0; mi < 4; ++mi)
#pragma unroll
                for (int ni = 0; ni < NI; ++ni)
                    acc[mi][ni] = __builtin_amdgcn_mfma_f32_16x16x32_bf16(
                        bfr[ni], af[mi], acc[mi][ni], 0, 0, 0);   // SWAPPED: C^T frag
        }
        __syncthreads();
    }

    // epilogue: acc[mi][ni][r] = C[row0+wr+mi*16+mrow][col0+wc+ni*16+quad*4+r]
    const int quad = lane >> 4;
#pragma unroll
    for (int ni = 0; ni < NI; ++ni) {
        const int col = col0 + wc + ni * 16 + quad * 4;
        F4 bv4; bv4.v = *(const float4*)&bias[col];
#pragma unroll
        for (int mi = 0; mi < 4; ++mi) {
            const int row = row0 + wr + mi * 16 + mrow;
            F4 o;
#pragma unroll
            for (int r = 0; r < 4; ++r) o.f[r] = acc[mi][ni][r] + bv4.f[r];
            if (RES) {
                F4 rr; rr.v = *(const float4*)&R[(size_t)row * N + col];
#pragma unroll
                for (int r = 0; r < 4; ++r) o.f[r] += rr.f[r];
            }
#pragma unroll
            for (int r = 0; r < 4; ++r) {
                o.f[r] *= sc;
                if (RELU) o.f[r] = fmaxf(o.f[r], 0.0f);
            }
            if (OUT_BF16) {
                bf16x4 ob;
#pragma unroll
                for (int r = 0; r < 4; ++r) ob[r] = (bf16)o.f[r];
                *(bf16x4*)&((bf16*)C)[(size_t)row * N + col] = ob;
            } else {
                *(float4*)&((float*)C)[(size_t)row * N + col] = o.v;
            }
        }
    }
}

// ---------------- Transposed-S MFMA flash attention (shfl-free PV + MFMA-fused l) ----------------
// r0 structure (proven fastest of 3 tested) + two isolated proven adds:
//   T5 setprio(1) around both MFMA clusters (m191: +4-7% attn)
//   T13 defer-max: gate the alpha rescale on __any(mloc > m_run + 8)
// grid (32,H,B) = 768 paired-uniform blocks; double-buffered K/V, 1 barrier/iter.
__global__ __launch_bounds__(256) void mattn_kernel(
    const bf16* __restrict__ Q, const bf16* __restrict__ K,
    const bf16* __restrict__ V, const int* __restrict__ amask,
    bf16* __restrict__ O) {
    const int bx = blockIdx.x, h = blockIdx.y, b = blockIdx.z;

    __shared__ bf16 Ks[2][64][68];   // [buf][key][d]  (136 B rows: conflict-free)
#if HAVE_MFMA16
    __shared__ bf16 Vt[2][80][68];   // [buf][d][key]; row 64 = ones (l fusion)
#else
    __shared__ bf16 Vt[2][64][68];
#endif
    __shared__ bf16 Os[64][68];      // epilogue bounce
    __shared__ float mk[2][64];
    __shared__ int flagv[2];

    const int tid = threadIdx.x;
    const int wave = tid >> 6, lane = tid & 63;
    const int l = lane & 15, quad = lane >> 4;
#if !HAVE_MFMA16
    const int qh = quad >> 1;
    const int srcA = (quad & 1) * 32 + l;
    const int srcB = srcA + 16;
#endif
    const float NEG_INF = -__builtin_huge_valf();

    const int kr = tid >> 2, ks = (tid & 3) * 16;          // K tile staging
    const int vk0 = (tid & 31) * 2, vds = (tid >> 5) * 8;  // V transpose staging

    const bf16* Kbase = K + (size_t)b * S_LEN * DMODEL + h * HDIM;
    const bf16* Vbase = V + (size_t)b * S_LEN * DMODEL + h * HDIM;

#if HAVE_MFMA16
    // ones row for l-fusion (row 64 of both V^T buffers); staging never touches
    // rows >= 64, so this survives the whole kernel. Visible after first barrier.
    if (tid < 68) {
        Vt[0][64][tid] = (bf16)1.0f;
        Vt[1][64][tid] = (bf16)1.0f;
    }
#endif

#pragma unroll 1
    for (int pass = 0; pass < 2; ++pass) {
        const int qt = pass ? bx : (63 - bx);

        const bf16* Qb = Q + (size_t)(b * S_LEN + qt * 64 + wave * 16 + l) * DMODEL + h * HDIM;
        const bf16x8 qf0 = *(const bf16x8*)(Qb + quad * 8);
        const bf16x8 qf1 = *(const bf16x8*)(Qb + 32 + quad * 8);

        float m_run = NEG_INF;
#if !HAVE_MFMA16
        float l_run = 0.0f;
#endif
        f32x4 acc[4] = {};
#if HAVE_MFMA16
        f32x4 acc_l = {};   // D-row 0 (quad-0 lanes, elem 0) accumulates l
#endif

        // ---- prefetch tile 0 into registers ----
        bf16x8 kp0, kp1, vp0, vp1;
        int mv = 1;
        {
            const bf16* kg = Kbase + (size_t)kr * DMODEL + ks;
            kp0 = *(const bf16x8*)kg;
            kp1 = *(const bf16x8*)(kg + 8);
            const bf16* vg = Vbase + (size_t)vk0 * DMODEL + vds;
            vp0 = *(const bf16x8*)vg;
            vp1 = *(const bf16x8*)(vg + DMODEL);
            if (wave == 0) mv = amask[b * S_LEN + lane];
        }
        __syncthreads();   // prior pass epilogue LDS reads complete
        {
            *(bf16x8*)&Ks[0][kr][ks]     = kp0;
            *(bf16x8*)&Ks[0][kr][ks + 8] = kp1;
#pragma unroll
            for (int i = 0; i < 8; ++i) {
                U2 w; w.h[0] = vp0[i]; w.h[1] = vp1[i];
                *(unsigned*)&Vt[0][vds + i][vk0] = w.u;
            }
            if (wave == 0) {
                mk[0][lane] = mv ? 0.0f : NEG_INF;
                unsigned long long bal = __ballot(mv != 0);
                if (lane == 0) flagv[0] = (bal == ~0ULL);
            }
        }
        __syncthreads();
        int buf = 0;

        for (int kt = 0; kt <= qt; ++kt) {
            const bool more = (kt < qt);
            if (more) {
                const bf16* kg = Kbase + (size_t)((kt + 1) * 64 + kr) * DMODEL + ks;
                kp0 = *(const bf16x8*)kg;
                kp1 = *(const bf16x8*)(kg + 8);
                const bf16* vg = Vbase + (size_t)((kt + 1) * 64 + vk0) * DMODEL + vds;
                vp0 = *(const bf16x8*)vg;
                vp1 = *(const bf16x8*)(vg + DMODEL);
                if (wave == 0) mv = amask[b * S_LEN + (kt + 1) * 64 + lane];
            }

            const int allv = flagv[buf];
            f32x4 sreg[4] = {};
            __builtin_amdgcn_s_setprio(1);
#pragma unroll
            for (int mi = 0; mi < 4; ++mi) {
                bf16x8 kf0 = *(const bf16x8*)&Ks[buf][mi * 16 + l][quad * 8];
                bf16x8 kf1 = *(const bf16x8*)&Ks[buf][mi * 16 + l][32 + quad * 8];
                sreg[mi] = __builtin_amdgcn_mfma_f32_16x16x32_bf16(kf0, qf0, sreg[mi], 0, 0, 0);
                sreg[mi] = __builtin_amdgcn_mfma_f32_16x16x32_bf16(kf1, qf1, sreg[mi], 0, 0, 0);
            }
            __builtin_amdgcn_s_setprio(0);
            if (!allv) {
#pragma unroll
                for (int mi = 0; mi < 4; ++mi) {
                    F4 m4; m4.v = *(const float4*)&mk[buf][mi * 16 + quad * 4];
#pragma unroll
                    for (int r = 0; r < 4; ++r) sreg[mi][r] += m4.f[r];
                }
            }
            if (kt == qt) {
#pragma unroll
                for (int mi = 0; mi < 4; ++mi)
#pragma unroll
                    for (int r = 0; r < 4; ++r)
                        if (mi * 16 + quad * 4 + r > wave * 16 + l)
                            sreg[mi][r] = NEG_INF;
            }

            // online softmax: max-reduce (15 max + 2 shfl); T13 defer-max gate.
            float mloc = sreg[0][0];
#pragma unroll
            for (int mi = 0; mi < 4; ++mi)
#pragma unroll
                for (int r = 0; r < 4; ++r) mloc = fmaxf(mloc, sreg[mi][r]);
            mloc = fmaxf(mloc, __shfl_xor(mloc, 16, 64));
            mloc = fmaxf(mloc, __shfl_xor(mloc, 32, 64));
            if (__any(mloc > m_run + 8.0f)) {
                const float mn = fmaxf(m_run, mloc);
                const float alpha = __builtin_amdgcn_exp2f(m_run - mn);
                m_run = mn;
#pragma unroll
                for (int mi = 0; mi < 4; ++mi)
#pragma unroll
                    for (int r = 0; r < 4; ++r) acc[mi][r] *= alpha;
#if HAVE_MFMA16
#pragma unroll
                for (int r = 0; r < 4; ++r) acc_l[r] *= alpha;
#else
                l_run *= alpha;
#endif
            }
#pragma unroll
            for (int mi = 0; mi < 4; ++mi)
#pragma unroll
                for (int r = 0; r < 4; ++r)
                    sreg[mi][r] = __builtin_amdgcn_exp2f(sreg[mi][r] - m_run);
#if !HAVE_MFMA16
            float ls = 0.0f;
#pragma unroll
            for (int mi = 0; mi < 4; ++mi)
#pragma unroll
                for (int r = 0; r < 4; ++r) ls += sreg[mi][r];
            ls += __shfl_xor(ls, 16, 64);
            ls += __shfl_xor(ls, 32, 64);
            l_run += ls;
#endif

            // pack P^T to bf16 dwords (keys mi*16+quad*4+{0..3}, query l)
            unsigned pk[4][2];
#pragma unroll
            for (int mi = 0; mi < 4; ++mi) {
                U2 w0; w0.h[0] = (bf16)sreg[mi][0]; w0.h[1] = (bf16)sreg[mi][1];
                U2 w1; w1.h[0] = (bf16)sreg[mi][2]; w1.h[1] = (bf16)sreg[mi][3];
                pk[mi][0] = w0.u; pk[mi][1] = w1.u;
            }

#if HAVE_MFMA16
            // O^T += V^T · P^T ; extra MFMA on ones-row accumulates l into acc_l.
            __builtin_amdgcn_s_setprio(1);
#pragma unroll
            for (int mi = 0; mi < 4; ++mi) {
                U4 pb; pb.u[0] = pk[mi][0]; pb.u[1] = pk[mi][1];
#pragma unroll
                for (int di = 0; di < 4; ++di) {
                    mf16_t va = *(const mf16_t*)&Vt[buf][di * 16 + l][mi * 16 + quad * 4];
                    acc[di] = MFMA16(va, pb.v, acc[di]);
                }
                mf16_t vl = *(const mf16_t*)&Vt[buf][64 + l][mi * 16 + quad * 4];
                acc_l = MFMA16(vl, pb.v, acc_l);
            }
            __builtin_amdgcn_s_setprio(0);
#else
            bf16x8 pfrag[2];
#pragma unroll
            for (int kc = 0; kc < 2; ++kc) {
                U8 u;
#pragma unroll
                for (int t = 0; t < 2; ++t) {
                    const unsigned a0 = (unsigned)__shfl((int)pk[2 * kc][t],     srcA, 64);
                    const unsigned b0 = (unsigned)__shfl((int)pk[2 * kc + 1][t], srcA, 64);
                    u.u[t] = qh ? b0 : a0;
                    const unsigned a1 = (unsigned)__shfl((int)pk[2 * kc][t],     srcB, 64);
                    const unsigned b1 = (unsigned)__shfl((int)pk[2 * kc + 1][t], srcB, 64);
                    u.u[2 + t] = qh ? b1 : a1;
                }
                pfrag[kc] = u.v;
            }
#pragma unroll
            for (int mi = 0; mi < 4; ++mi) {
                bf16x8 vf0 = *(const bf16x8*)&Vt[buf][mi * 16 + l][quad * 8];
                bf16x8 vf1 = *(const bf16x8*)&Vt[buf][mi * 16 + l][32 + quad * 8];
                acc[mi] = __builtin_amdgcn_mfma_f32_16x16x32_bf16(vf0, pfrag[0], acc[mi], 0, 0, 0);
                acc[mi] = __builtin_amdgcn_mfma_f32_16x16x32_bf16(vf1, pfrag[1], acc[mi], 0, 0, 0);
            }
#endif

            if (more) {
                const int nb = buf ^ 1;
                *(bf16x8*)&Ks[nb][kr][ks]     = kp0;
                *(bf16x8*)&Ks[nb][kr][ks + 8] = kp1;
#pragma unroll
                for (int i = 0; i < 8; ++i) {
                    U2 w; w.h[0] = vp0[i]; w.h[1] = vp1[i];
                    *(unsigned*)&Vt[nb][vds + i][vk0] = w.u;
                }
                if (wave == 0) {
                    mk[nb][lane] = mv ? 0.0f : NEG_INF;
                    unsigned long long bal = __ballot(mv != 0);
                    if (lane == 0) flagv[nb] = (bal == ~0ULL);
                }
            }
            __syncthreads();
            buf ^= 1;
        }

#if HAVE_MFMA16
        // l lives in acc_l[0] of quad-0 lane with col==query; broadcast via shfl.
        const float l_run = __shfl(acc_l[0], l, 64);
#endif
        const float rinv = 1.0f / l_run;
#pragma unroll
        for (int mi = 0; mi < 4; ++mi) {
            U2 w0; w0.h[0] = (bf16)(acc[mi][0] * rinv); w0.h[1] = (bf16)(acc[mi][1] * rinv);
            U2 w1; w1.h[0] = (bf16)(acc[mi][2] * rinv); w1.h[1] = (bf16)(acc[mi][3] * rinv);
            *(unsigned*)&Os[wave * 16 + l][mi * 16 + quad * 4]     = w0.u;
            *(unsigned*)&Os[wave * 16 + l][mi * 16 + quad * 4 + 2] = w1.u;
        }
        __syncthreads();
        {
            const int orow = tid >> 2, oseg = (tid & 3) * 16;
            bf16* Og = O + (size_t)(b * S_LEN + qt * 64 + orow) * DMODEL + h * HDIM + oseg;
            *(bf16x8*)Og       = *(const bf16x8*)&Os[orow][oseg];
            *(bf16x8*)(Og + 8) = *(const bf16x8*)&Os[orow][oseg + 8];
        }
    }
}

// ---------------- launcher ----------------
extern "C" void kernel_launch(void* const* d_in, const int* in_sizes, int n_in,
                              void* d_out, int out_size, void* d_ws, size_t ws_size,
                              hipStream_t stream) {
    const float* x     = (const float*)d_in[0];
    const int*   amask = (const int*)  d_in[1];
    const float* ln1_g = (const float*)d_in[2];
    const float* ln1_b = (const float*)d_in[3];
    const float* ln2_g = (const float*)d_in[4];
    const float* ln2_b = (const float*)d_in[5];
    const float* Wq = (const float*)d_in[6];  const float* bq = (const float*)d_in[7];
    const float* Wk = (const float*)d_in[8];  const float* bk = (const float*)d_in[9];
    const float* Wv = (const float*)d_in[10]; const float* bv = (const float*)d_in[11];
    const float* Wo = (const float*)d_in[12]; const float* bo = (const float*)d_in[13];
    const float* W1 = (const float*)d_in[14]; const float* b1 = (const float*)d_in[15];
    const float* W2 = (const float*)d_in[16]; const float* b2 = (const float*)d_in[17];
    float* out = (float*)d_out;

    char* ws = (char*)d_ws;
    const size_t WSML = (size_t)DMODEL * DMODEL * 2;
    const size_t WBIG = (size_t)DMODEL * DFF_ * 2;
    bf16* Wqt = (bf16*)(ws + 0 * WSML);
    bf16* Wkt = (bf16*)(ws + 1 * WSML);
    bf16* Wvt = (bf16*)(ws + 2 * WSML);
    bf16* Wot = (bf16*)(ws + 3 * WSML);
    bf16* W1t = (bf16*)(ws + 4 * WSML);
    bf16* W2t = (bf16*)(ws + 4 * WSML + WBIG);
    char* act = ws + 4 * WSML + 2 * WBIG;

    const size_t HB = (size_t)MROWS * DMODEL * 2;   // bf16 activation (12.6 MB)
    const size_t FB = (size_t)MROWS * DMODEL * 4;   // fp32 activation (25.2 MB)
    bf16*  h    = (bf16*)(act);            // LN1 out; later ctx; later h2
    bf16*  qb   = (bf16*)(act + HB);
    bf16*  kb   = (bf16*)(act + 2 * HB);
    bf16*  vb   = (bf16*)(act + 3 * HB);
    bf16*  ctx  = h;
    float* x1   = (float*)(act + 4 * HB);
    bf16*  f    = (bf16*)(act + 4 * HB + FB);      // FF1 out (50.3 MB)
    bf16*  h2   = h;

    const float SCL = 0.125f * 1.44269504089f;  // 1/sqrt(64) * log2(e), folded into Q

    // 0. fused weight transpose+convert (one launch, 1728 tiles)
    wtrans_all_kernel<<<1728, 256, 0, stream>>>(Wq, Wk, Wv, Wo, W1, W2,
                                                Wqt, Wkt, Wvt, Wot, W1t, W2t);

    // 1. LN1 -> h (bf16)
    ln_kernel<bf16><<<MROWS, 256, 0, stream>>>(x, ln1_g, ln1_b, h, nullptr);
    // 2. QKV fused, bf16 out; Q pre-scaled by SCL  (1152 blocks)
    mgemm_kernel<128, false, false, true><<<dim3(DMODEL / 128, MROWS / 128, 3), 256, 0, stream>>>(
        h, Wqt, bq, qb, Wkt, bk, kb, Wvt, bv, vb, nullptr,
        MROWS, DMODEL, DMODEL, DMODEL, 0, 0, 0, SCL, 1.0f, 1.0f);
    // 3. flash attention -> ctx (bf16)  (768 paired-uniform blocks)
    mattn_kernel<<<dim3(32, NHEAD, 2), 256, 0, stream>>>(qb, kb, vb, amask, ctx);
    // 4. out proj + residual(x) -> x1 (fp32)  (MT=64: 768 blocks)
    mgemm_kernel<64, false, true, false><<<dim3(DMODEL / 128, MROWS / 64, 1), 256, 0, stream>>>(
        ctx, Wot, bo, x1, Wot, bo, x1, Wot, bo, x1, x,
        MROWS, DMODEL, DMODEL, DMODEL, 0, 0, 0, 1.0f, 1.0f, 1.0f);
    // 5. LN2 -> h2 (bf16)
    ln_kernel<bf16><<<MROWS, 256, 0, stream>>>(x1, ln2_g, ln2_b, h2, nullptr);
    // 6. FF1 + relu -> f (bf16)  (1536 blocks)
    mgemm_kernel<128, true, false, true><<<dim3(DFF_ / 128, MROWS / 128, 1), 256, 0, stream>>>(
        h2, W1t, b1, f, W1t, b1, f, W1t, b1, f, nullptr,
        MROWS, DFF_, DMODEL, DMODEL, 0, 0, 0, 1.0f, 1.0f, 1.0f);
    // 7. FF2 full-K, MT=64 (768 blocks): out = f@W2 + b2 + x1, fp32 direct.
    mgemm_kernel<64, false, true, false><<<dim3(DMODEL / 128, MROWS / 64, 1), 256, 0, stream>>>(
        f, W2t, b2, out, W2t, b2, out, W2t, b2, out, x1,
        MROWS, DMODEL, DFF_, DFF_, 0, 0, 0, 1.0f, 1.0f, 1.0f);
}